// Round 3
// baseline (1875.280 us; speedup 1.0000x reference)
//
#include <hip/hip_runtime.h>
#include <cstdint>
#include <cstddef>

// Problem constants
#define BDIM 2
#define CDIM 512
#define HDIM 128
#define WDIM 128
#define NDIM (HDIM * WDIM)        // 16384
#define LNUM 6
#define NHEADS 8
#define HEAD_DIM 64
#define NPTS 4
#define BN_TOT (BDIM * NDIM)      // 32768

typedef unsigned short u16;
typedef __attribute__((ext_vector_type(8))) short bf16x8;   // 8 bf16 = 4 VGPRs
typedef __attribute__((ext_vector_type(4))) float f32x4;    // MFMA accum

__device__ __forceinline__ u16 f2bf(float x) {              // RNE fp32->bf16
    unsigned u = __float_as_uint(x);
    u += 0x7fffu + ((u >> 16) & 1u);
    return (u16)(u >> 16);
}
__device__ __forceinline__ float bf2f(u16 h) {
    return __uint_as_float(((unsigned)h) << 16);
}

__device__ __forceinline__ void load_lds16(const void* g, void* l) {
    // async global->LDS, 16B/lane; LDS dest = wave-uniform base + lane*16
    __builtin_amdgcn_global_load_lds(
        (const __attribute__((address_space(1))) void*)g,
        (__attribute__((address_space(3))) void*)l, 16, 0, 0);
}

// counted vmem waits (literal-only in asm string)
__device__ __forceinline__ void wait_vm8() { asm volatile("s_waitcnt vmcnt(8)" ::: "memory"); }
__device__ __forceinline__ void wait_vm5() { asm volatile("s_waitcnt vmcnt(5)" ::: "memory"); }
__device__ __forceinline__ void wait_vm4() { asm volatile("s_waitcnt vmcnt(4)" ::: "memory"); }
__device__ __forceinline__ void wait_vm0() { asm volatile("s_waitcnt vmcnt(0)" ::: "memory"); }
__device__ __forceinline__ void sbar()  { __builtin_amdgcn_s_barrier(); }
__device__ __forceinline__ void spin()  { __builtin_amdgcn_sched_barrier(0); }

// ---------------------------------------------------------------------------
// voxelization: mask / order / ref / pack_q(bf16)
// ---------------------------------------------------------------------------
__global__ void mask_kernel(const float* __restrict__ lidar, int* __restrict__ mask)
{
    int idx = blockIdx.x * blockDim.x + threadIdx.x;
    if (idx >= BN_TOT) return;
    int b = idx / NDIM;
    int n = idx - b * NDIM;
    const float* p = lidar + (size_t)b * CDIM * NDIM + n;
    int ok = 1;
#pragma unroll 8
    for (int c = 0; c < CDIM; ++c)
        ok &= (p[(size_t)c * NDIM] != 0.0f);
    mask[idx] = ok;
}

__global__ void order_kernel(const int* __restrict__ mask, int* __restrict__ order,
                             int* __restrict__ nvalid)
{
    int b = blockIdx.x;
    const int* m = mask + b * NDIM;
    int* ord = order + b * NDIM;
    __shared__ int part[256];
    __shared__ int totalValid;
    int t = threadIdx.x;
    const int CHUNK = NDIM / 256;
    int base = t * CHUNK;
    int cnt = 0;
    for (int i = 0; i < CHUNK; ++i) cnt += m[base + i];
    part[t] = cnt;
    __syncthreads();
    for (int s = 1; s < 256; s <<= 1) {
        int v = (t >= s) ? part[t - s] : 0;
        __syncthreads();
        part[t] += v;
        __syncthreads();
    }
    if (t == 255) { totalValid = part[255]; nvalid[b] = part[255]; }
    __syncthreads();
    int validBefore = (t == 0) ? 0 : part[t - 1];
    int nv = totalValid;
    for (int i = 0; i < CHUNK; ++i) {
        int n = base + i;
        if (m[n]) { ord[validBefore] = n; validBefore++; }
        else      { int invBefore = n - validBefore; ord[nv + invBefore] = n; }
    }
}

__global__ void ref_kernel(const int* __restrict__ order, const int* __restrict__ nvalid,
                           float* __restrict__ ref)
{
    int idx = blockIdx.x * blockDim.x + threadIdx.x;
    if (idx >= BN_TOT) return;
    int b = idx / NDIM;
    int j = idx - b * NDIM;
    int n = order[idx];
    float flag = (j < nvalid[b]) ? 1.0f : 0.0f;
    int hh = n / WDIM;
    int ww = n - hh * WDIM;
    ref[(size_t)idx * 2 + 0] = ((float)ww / (float)WDIM) * flag;
    ref[(size_t)idx * 2 + 1] = ((float)hh / (float)HDIM) * flag;
}

__global__ void pack_q_kernel(const float* __restrict__ lidar, const int* __restrict__ order,
                              const int* __restrict__ nvalid, u16* __restrict__ q)
{
    __shared__ float tile[32][33];
    __shared__ int ord_s[32];
    int b  = blockIdx.z;
    int j0 = blockIdx.x * 32;
    int c0 = blockIdx.y * 32;
    int tx = threadIdx.x, ty = threadIdx.y;
    if (ty == 0) ord_s[tx] = order[b * NDIM + j0 + tx];
    __syncthreads();
    const float* src = lidar + (size_t)b * CDIM * NDIM;
#pragma unroll
    for (int k = 0; k < 4; ++k) {
        int cl = ty * 4 + k;
        tile[cl][tx] = src[(size_t)(c0 + cl) * NDIM + ord_s[tx]];
    }
    __syncthreads();
    int nv = nvalid[b];
#pragma unroll
    for (int k = 0; k < 4; ++k) {
        int jl = ty * 4 + k;
        int j = j0 + jl;
        float f = (j < nv) ? 1.0f : 0.0f;
        q[((size_t)b * NDIM + j) * CDIM + c0 + tx] = f2bf(tile[tx][jl] * f);
    }
}

// final scatter: out[b,c,order[j]] = q(bf16)[b,j,c] * valid  (fp32 out)
__global__ void scatter_kernel(const u16* __restrict__ q, const int* __restrict__ order,
                               const int* __restrict__ nvalid, float* __restrict__ out)
{
    __shared__ float tile[32][33];
    __shared__ int ord_s[32];
    int b  = blockIdx.z;
    int j0 = blockIdx.x * 32;
    int c0 = blockIdx.y * 32;
    int tx = threadIdx.x, ty = threadIdx.y;
    if (ty == 0) ord_s[tx] = order[b * NDIM + j0 + tx];
    __syncthreads();
    int nv = nvalid[b];
#pragma unroll
    for (int k = 0; k < 4; ++k) {
        int jl = ty * 4 + k;
        int j = j0 + jl;
        float f = (j < nv) ? 1.0f : 0.0f;
        tile[jl][tx] = bf2f(q[((size_t)b * NDIM + j) * CDIM + c0 + tx]) * f;
    }
    __syncthreads();
    float* dst = out + (size_t)b * CDIM * NDIM;
#pragma unroll
    for (int k = 0; k < 4; ++k) {
        int cl = ty * 4 + k;
        dst[(size_t)(c0 + cl) * NDIM + ord_s[tx]] = tile[tx][cl];
    }
}

// ---------------------------------------------------------------------------
// batched weight transpose-convert: src fp32 [z][512][512] -> dst bf16 [z][N][K]
// ---------------------------------------------------------------------------
__global__ void tconv_b_kernel(const float* __restrict__ src0, u16* __restrict__ dst0)
{
    __shared__ float t[32][33];
    int z = blockIdx.z;
    const float* src = src0 + (size_t)z * 512 * 512;
    u16* dst = dst0 + (size_t)z * 512 * 512;
    int k0 = blockIdx.x * 32, n0 = blockIdx.y * 32;
    int tx = threadIdx.x, ty = threadIdx.y;
#pragma unroll
    for (int j = 0; j < 4; ++j) {
        int kl = ty * 4 + j;
        t[kl][tx] = src[(size_t)(k0 + kl) * 512 + n0 + tx];
    }
    __syncthreads();
#pragma unroll
    for (int j = 0; j < 4; ++j) {
        int nl = ty * 4 + j;
        dst[(size_t)(n0 + nl) * 512 + k0 + tx] = f2bf(t[tx][nl]);
    }
}

// batched: Woff [z][512][64] + Waw [z][512][32] -> dst bf16 [z][96][512]
__global__ void tconv_offaw_b_kernel(const float* __restrict__ woff0,
                                     const float* __restrict__ waw0,
                                     u16* __restrict__ dst0)
{
    __shared__ float t[32][33];
    int z = blockIdx.z;
    const float* woff = woff0 + (size_t)z * 512 * 64;
    const float* waw  = waw0 + (size_t)z * 512 * 32;
    u16* dst = dst0 + (size_t)z * 96 * 512;
    int k0 = blockIdx.x * 32, n0 = blockIdx.y * 32;
    int tx = threadIdx.x, ty = threadIdx.y;
#pragma unroll
    for (int j = 0; j < 4; ++j) {
        int kl = ty * 4 + j;
        int n = n0 + tx;
        float v = (n < 64) ? woff[(size_t)(k0 + kl) * 64 + n]
                           : waw[(size_t)(k0 + kl) * 32 + (n - 64)];
        t[kl][tx] = v;
    }
    __syncthreads();
#pragma unroll
    for (int j = 0; j < 4; ++j) {
        int nl = ty * 4 + j;
        dst[(size_t)(n0 + nl) * 512 + k0 + tx] = f2bf(t[tx][nl]);
    }
}

// bev (B,C,N) fp32 -> featT (B,N,C) bf16
__global__ void bev_conv_kernel(const float* __restrict__ bev, u16* __restrict__ dst)
{
    __shared__ float t[32][33];
    int b  = blockIdx.z;
    int n0 = blockIdx.x * 32;
    int c0 = blockIdx.y * 32;
    int tx = threadIdx.x, ty = threadIdx.y;
    const float* src = bev + (size_t)b * CDIM * NDIM;
#pragma unroll
    for (int j = 0; j < 4; ++j) {
        int cl = ty * 4 + j;
        t[cl][tx] = src[(size_t)(c0 + cl) * NDIM + n0 + tx];
    }
    __syncthreads();
#pragma unroll
    for (int j = 0; j < 4; ++j) {
        int nl = ty * 4 + j;
        dst[((size_t)b * NDIM + n0 + nl) * CDIM + c0 + tx] = f2bf(t[tx][nl]);
    }
}

// ---------------------------------------------------------------------------
// PE hidden: h = relu(BN(ref @ pe_W1))  -> bf16
// ---------------------------------------------------------------------------
__global__ void pe_hidden_kernel(const float* __restrict__ ref, const float* __restrict__ W1,
                                 const float* __restrict__ g, const float* __restrict__ bb,
                                 const float* __restrict__ m, const float* __restrict__ v,
                                 u16* __restrict__ out)
{
    int row = blockIdx.x;
    float r0 = ref[(size_t)row * 2 + 0];
    float r1 = ref[(size_t)row * 2 + 1];
    for (int c = threadIdx.x; c < CDIM; c += blockDim.x) {
        float pe = r0 * W1[c] + r1 * W1[CDIM + c];
        pe = (pe - m[c]) * rsqrtf(v[c] + 1e-5f) * g[c] + bb[c];
        out[(size_t)row * CDIM + c] = f2bf(fmaxf(pe, 0.0f));
    }
}

// ---------------------------------------------------------------------------
// x = q(bf16) + qpos(bf16) -> bf16 ; 8 elements/thread (layer-0 only)
// ---------------------------------------------------------------------------
__global__ void add_bf_kernel(const u16* __restrict__ q, const u16* __restrict__ qpos,
                              u16* __restrict__ x)
{
    size_t i = (size_t)blockIdx.x * blockDim.x + threadIdx.x;  // 8-el group
    uint4 qa = ((const uint4*)q)[i];
    uint4 pv = ((const uint4*)qpos)[i];
    unsigned qw[4] = {qa.x, qa.y, qa.z, qa.w};
    unsigned pw[4] = {pv.x, pv.y, pv.z, pv.w};
    unsigned rw[4];
#pragma unroll
    for (int k = 0; k < 4; ++k) {
        float a0 = bf2f((u16)(qw[k] & 0xffff)), a1 = bf2f((u16)(qw[k] >> 16));
        float p0 = bf2f((u16)(pw[k] & 0xffff)), p1 = bf2f((u16)(pw[k] >> 16));
        rw[k] = (unsigned)f2bf(a0 + p0) | ((unsigned)f2bf(a1 + p1) << 16);
    }
    uint4 r; r.x = rw[0]; r.y = rw[1]; r.z = rw[2]; r.w = rw[3];
    ((uint4*)x)[i] = r;
}

// ---------------------------------------------------------------------------
// MFMA bf16 GEMM. 128x128 tile, BK=32, 4 waves.
// v4: NON-redundant wave staging (each wave stages 2 A-chunks + 2 B-chunks it
// may not read itself) + two raw barriers per K-step + counted vmcnt:
//   s_barrier (prev readers of nxt done) -> issue nxt (4 DMA) -> vmcnt(4)
//   (own cur loads done) -> s_barrier (ALL cur loads done) -> ds_read + MFMA.
// Cross-wave safety: every wave passes vmcnt(4) before barrier 2, so all
// staging for cur is complete when any wave reads it. Staged bytes/step
// halved vs v3 (no duplicate panels).
// ---------------------------------------------------------------------------
__global__ __launch_bounds__(256) void gemm_bf16(
    const u16* __restrict__ A, const u16* __restrict__ Bt,
    const float* __restrict__ bias, u16* __restrict__ outB, int relu)
{
    __shared__ u16 As[2][128 * 32];
    __shared__ u16 Bs[2][128 * 32];
    int tid = threadIdx.x;
    int wave = tid >> 6, lane = tid & 63;
    int wr = wave >> 1, wc = wave & 1;
    int quad = lane >> 4, l15 = lane & 15;
    int bm = blockIdx.y * 128, bn = blockIdx.x * 128;

    f32x4 acc[4][4];
#pragma unroll
    for (int i = 0; i < 4; ++i)
#pragma unroll
        for (int j = 0; j < 4; ++j) { f32x4 z = {0.f, 0.f, 0.f, 0.f}; acc[i][j] = z; }

    // non-redundant staging: 8 A-chunks + 8 B-chunks of 16 rows; wave w owns
    // chunks {w, w+4}. lane -> (row=lane>>2, col=(lane&3)*8) within chunk.
    int ch0 = wave, ch1 = wave + 4;
    const u16* Ag0 = A  + (size_t)(bm + ch0 * 16 + (lane >> 2)) * 512 + (lane & 3) * 8;
    const u16* Ag1 = A  + (size_t)(bm + ch1 * 16 + (lane >> 2)) * 512 + (lane & 3) * 8;
    const u16* Bg0 = Bt + (size_t)(bn + ch0 * 16 + (lane >> 2)) * 512 + (lane & 3) * 8;
    const u16* Bg1 = Bt + (size_t)(bn + ch1 * 16 + (lane >> 2)) * 512 + (lane & 3) * 8;

    // prologue: stage tile 0 into buffer 0
    load_lds16(Ag0, &As[0][ch0 * 512]);
    load_lds16(Ag1, &As[0][ch1 * 512]);
    load_lds16(Bg0, &Bs[0][ch0 * 512]);
    load_lds16(Bg1, &Bs[0][ch1 * 512]);

    for (int it = 0; it < 16; ++it) {
        sbar();  spin();                    // prev readers of nxt done
        int cur = it & 1, nxt = cur ^ 1;
        if (it < 15) {
            int kn = (it + 1) * 32;
            load_lds16(Ag0 + kn, &As[nxt][ch0 * 512]);
            load_lds16(Ag1 + kn, &As[nxt][ch1 * 512]);
            load_lds16(Bg0 + kn, &Bs[nxt][ch0 * 512]);
            load_lds16(Bg1 + kn, &Bs[nxt][ch1 * 512]);
            wait_vm4();                     // own cur loads landed; nxt in flight
        } else {
            wait_vm0();
        }
        sbar();  spin();                    // everyone's cur loads landed
        bf16x8 av[4], bv[4];
#pragma unroll
        for (int mi = 0; mi < 4; ++mi)
            av[mi] = *(const bf16x8*)&As[cur][(wr * 64 + mi * 16 + l15) * 32 + quad * 8];
#pragma unroll
        for (int ni = 0; ni < 4; ++ni)
            bv[ni] = *(const bf16x8*)&Bs[cur][(wc * 64 + ni * 16 + l15) * 32 + quad * 8];
#pragma unroll
        for (int mi = 0; mi < 4; ++mi)
#pragma unroll
            for (int ni = 0; ni < 4; ++ni)
                acc[mi][ni] = __builtin_amdgcn_mfma_f32_16x16x32_bf16(
                    av[mi], bv[ni], acc[mi][ni], 0, 0, 0);
    }

    int rowb = bm + wr * 64;
    int colb = bn + wc * 64;
#pragma unroll
    for (int mi = 0; mi < 4; ++mi) {
#pragma unroll
        for (int ni = 0; ni < 4; ++ni) {
            int col = colb + ni * 16 + l15;
            float bi = bias ? bias[col] : 0.0f;
#pragma unroll
            for (int r = 0; r < 4; ++r) {
                int row = rowb + mi * 16 + quad * 4 + r;
                float val = acc[mi][ni][r] + bi;
                if (relu) val = fmaxf(val, 0.0f);
                outB[(size_t)row * 512 + col] = f2bf(val);
            }
        }
    }
}

// ---------------------------------------------------------------------------
// fused GEMM + residual + LayerNorm (+ optional x = LN + qpos)
// v4: BM=128 (was 64), BN=512, 512 threads (8 waves, wave grid 2Mx4N,
// per-wave C = 64x128, acc[4][8]). NON-redundant staging: wave wv owns
// A-chunk wv and B-chunks wv*4..wv*4+3 (5 DMA/step). Two raw barriers +
// vmcnt(5) per K-step (same safety argument as gemm_bf16 v4).
// Staged bytes/FLOP cut 3.2x vs v3 (no 8x A duplication + 2x tile reuse).
// LDS 85KB -> 1 block/CU, grid = 256 blocks = 1/CU.
// ---------------------------------------------------------------------------
__global__ __launch_bounds__(512) void gemm_ln(
    const u16* __restrict__ A, const u16* __restrict__ Bt,
    const float* __restrict__ bias, const u16* __restrict__ resid,
    const float* __restrict__ g, const float* __restrict__ bta,
    u16* __restrict__ outQ, const u16* __restrict__ qpos, u16* __restrict__ outX)
{
    __shared__ u16 As[2][128 * 32];      // 16 KB
    __shared__ u16 Bs[2][512 * 32];      // 64 KB
    __shared__ float rs[8][64];
    __shared__ float rq[8][64];
    __shared__ float muL[128], invL[128];

    int tid = threadIdx.x;
    int wv = tid >> 6, lane = tid & 63;
    int quad = lane >> 4, l15 = lane & 15;
    int wr = wv >> 2, wc = wv & 3;       // wave grid 2 (M) x 4 (N)
    int bm = blockIdx.x * 128;

    f32x4 acc[4][8];
#pragma unroll
    for (int i = 0; i < 4; ++i)
#pragma unroll
        for (int j = 0; j < 8; ++j) { f32x4 z = {0.f, 0.f, 0.f, 0.f}; acc[i][j] = z; }

    // staging ownership: A-chunk wv (16 rows), B-chunks wv*4..+3 (4x16 rows)
    const u16* Ag = A + (size_t)(bm + wv * 16 + (lane >> 2)) * 512 + (lane & 3) * 8;
    const u16* Bg[4];
#pragma unroll
    for (int s = 0; s < 4; ++s)
        Bg[s] = Bt + (size_t)((wv * 4 + s) * 16 + (lane >> 2)) * 512 + (lane & 3) * 8;

    // prologue: stage tile 0 into buffer 0
    load_lds16(Ag, &As[0][wv * 512]);
#pragma unroll
    for (int s = 0; s < 4; ++s)
        load_lds16(Bg[s], &Bs[0][(wv * 4 + s) * 512]);

    for (int kk = 0; kk < 16; ++kk) {
        sbar();  spin();                    // prev readers of nxt done
        int cur = kk & 1, nxt = cur ^ 1;
        if (kk < 15) {
            int kn = (kk + 1) * 32;
            load_lds16(Ag + kn, &As[nxt][wv * 512]);
#pragma unroll
            for (int s = 0; s < 4; ++s)
                load_lds16(Bg[s] + kn, &Bs[nxt][(wv * 4 + s) * 512]);
            wait_vm5();                     // own cur loads landed; nxt in flight
        } else {
            wait_vm0();
        }
        sbar();  spin();                    // everyone's cur loads landed
        bf16x8 av[4], bv[8];
#pragma unroll
        for (int mi = 0; mi < 4; ++mi)
            av[mi] = *(const bf16x8*)&As[cur][(wr * 64 + mi * 16 + l15) * 32 + quad * 8];
#pragma unroll
        for (int ni = 0; ni < 8; ++ni)
            bv[ni] = *(const bf16x8*)&Bs[cur][(wc * 128 + ni * 16 + l15) * 32 + quad * 8];
#pragma unroll
        for (int mi = 0; mi < 4; ++mi)
#pragma unroll
            for (int ni = 0; ni < 8; ++ni)
                acc[mi][ni] = __builtin_amdgcn_mfma_f32_16x16x32_bf16(
                    av[mi], bv[ni], acc[mi][ni], 0, 0, 0);
    }

    // epilogue: val = acc + bias + resid
    int colb = wc * 128;
    float biasv[8], gv[8], btv[8];
#pragma unroll
    for (int ni = 0; ni < 8; ++ni) {
        int c = colb + ni * 16 + l15;
        biasv[ni] = bias ? bias[c] : 0.0f;
        gv[ni] = g[c];
        btv[ni] = bta[c];
    }
#pragma unroll
    for (int mi = 0; mi < 4; ++mi) {
#pragma unroll
        for (int r = 0; r < 4; ++r) {
            size_t rowoff = (size_t)(bm + wr * 64 + mi * 16 + quad * 4 + r) * 512;
#pragma unroll
            for (int ni = 0; ni < 8; ++ni) {
                int col = colb + ni * 16 + l15;
                acc[mi][ni][r] += biasv[ni] + bf2f(resid[rowoff + col]);
            }
        }
    }
    // row reduction: per (mi,r) sum across ni then across 16 lanes
#pragma unroll
    for (int mi = 0; mi < 4; ++mi) {
#pragma unroll
        for (int r = 0; r < 4; ++r) {
            float s = 0.f, s2 = 0.f;
#pragma unroll
            for (int ni = 0; ni < 8; ++ni) {
                s  += acc[mi][ni][r];
                s2 += acc[mi][ni][r] * acc[mi][ni][r];
            }
#pragma unroll
            for (int m = 1; m < 16; m <<= 1) {
                s  += __shfl_xor(s, m, 64);
                s2 += __shfl_xor(s2, m, 64);
            }
            if (l15 == 0) {
                rs[wv][mi * 16 + quad * 4 + r] = s;   // local row within wave: 0..63
                rq[wv][mi * 16 + quad * 4 + r] = s2;
            }
        }
    }
    __syncthreads();
    if (tid < 128) {                       // tid = wr*64 + local row
        int wrg = tid >> 6, lr = tid & 63;
        float s = 0.f, s2 = 0.f;
#pragma unroll
        for (int w4 = 0; w4 < 4; ++w4) {   // the 4 waves (wc) sharing this row
            int w = wrg * 4 + w4;
            s += rs[w][lr]; s2 += rq[w][lr];
        }
        float mu = s * (1.0f / 512.0f);
        float var = s2 * (1.0f / 512.0f) - mu * mu;
        muL[tid] = mu;
        invL[tid] = rsqrtf(var + 1e-5f);
    }
    __syncthreads();
#pragma unroll
    for (int mi = 0; mi < 4; ++mi) {
#pragma unroll
        for (int r = 0; r < 4; ++r) {
            int lrow = wr * 64 + mi * 16 + quad * 4 + r;   // 0..127
            float mu = muL[lrow], iv = invL[lrow];
            size_t rowoff = (size_t)(bm + lrow) * 512;
#pragma unroll
            for (int ni = 0; ni < 8; ++ni) {
                int col = colb + ni * 16 + l15;
                float y = (acc[mi][ni][r] - mu) * iv * gv[ni] + btv[ni];
                outQ[rowoff + col] = f2bf(y);
                if (outX)
                    outX[rowoff + col] = f2bf(y + bf2f(qpos[rowoff + col]));
            }
        }
    }
}

// ---------------------------------------------------------------------------
// fused off+aw GEMM (v3 schedule, kept): A @ OffAwT[96][512] -> offb/awb
// ---------------------------------------------------------------------------
__global__ __launch_bounds__(256) void gemm_offaw(
    const u16* __restrict__ A, const u16* __restrict__ Bt,
    const float* __restrict__ boff, const float* __restrict__ baw,
    u16* __restrict__ offb, u16* __restrict__ awb)
{
    __shared__ u16 As[2][128 * 32];
    __shared__ u16 Bs[2][128 * 32];
    int tid = threadIdx.x;
    int wave = tid >> 6, lane = tid & 63;
    int wr = wave >> 1, wc = wave & 1;
    int quad = lane >> 4, l15 = lane & 15;
    int bm = blockIdx.y * 128;

    f32x4 acc[4][4];
#pragma unroll
    for (int i = 0; i < 4; ++i)
#pragma unroll
        for (int j = 0; j < 4; ++j) { f32x4 z = {0.f, 0.f, 0.f, 0.f}; acc[i][j] = z; }

    // wave-local staging; B rows clamped at 95 (cols >=96 are discarded)
    const u16* Ag[4];
    const u16* Bg[4];
#pragma unroll
    for (int s = 0; s < 4; ++s) {
        Ag[s] = A + (size_t)(bm + wr * 64 + s * 16 + (lane >> 2)) * 512 + (lane & 3) * 8;
        int br = wc * 64 + s * 16 + (lane >> 2);
        if (br > 95) br = 95;
        Bg[s] = Bt + (size_t)br * 512 + (lane & 3) * 8;
    }

#pragma unroll
    for (int s = 0; s < 4; ++s) {
        load_lds16(Ag[s], &As[0][(wr * 4 + s) * 512]);
        load_lds16(Bg[s], &Bs[0][(wc * 4 + s) * 512]);
    }

    for (int it = 0; it < 16; ++it) {
        sbar();
        int cur = it & 1, nxt = cur ^ 1;
        if (it < 15) {
            int kn = (it + 1) * 32;
#pragma unroll
            for (int s = 0; s < 4; ++s) {
                load_lds16(Ag[s] + kn, &As[nxt][(wr * 4 + s) * 512]);
                load_lds16(Bg[s] + kn, &Bs[nxt][(wc * 4 + s) * 512]);
            }
            wait_vm8();
        } else {
            wait_vm0();
        }
        bf16x8 av[4], bv[4];
#pragma unroll
        for (int mi = 0; mi < 4; ++mi)
            av[mi] = *(const bf16x8*)&As[cur][(wr * 64 + mi * 16 + l15) * 32 + quad * 8];
#pragma unroll
        for (int ni = 0; ni < 4; ++ni)
            bv[ni] = *(const bf16x8*)&Bs[cur][(wc * 64 + ni * 16 + l15) * 32 + quad * 8];
#pragma unroll
        for (int mi = 0; mi < 4; ++mi)
#pragma unroll
            for (int ni = 0; ni < 4; ++ni)
                acc[mi][ni] = __builtin_amdgcn_mfma_f32_16x16x32_bf16(
                    av[mi], bv[ni], acc[mi][ni], 0, 0, 0);
    }

    int rowb = bm + wr * 64;
#pragma unroll
    for (int mi = 0; mi < 4; ++mi) {
#pragma unroll
        for (int ni = 0; ni < 4; ++ni) {
            int col = wc * 64 + ni * 16 + l15;
            if (col < 96) {
                float bi = (col < 64) ? boff[col] : baw[col - 64];
#pragma unroll
                for (int r = 0; r < 4; ++r) {
                    int row = rowb + mi * 16 + quad * 4 + r;
                    float val = acc[mi][ni][r] + bi;
                    if (col < 64) offb[(size_t)row * 64 + col] = f2bf(val);
                    else          awb[(size_t)row * 32 + (col - 64)] = f2bf(val);
                }
            }
        }
    }
}

// ---------------------------------------------------------------------------
// deformable sampling: one wave per (b,j); lane = (head, 8 channels)
// ---------------------------------------------------------------------------
__global__ __launch_bounds__(256) void sample_kernel(
    const float* __restrict__ ref, const u16* __restrict__ off,
    const u16* __restrict__ aw, const u16* __restrict__ v,
    u16* __restrict__ out)
{
    int bj = blockIdx.x * 4 + (threadIdx.x >> 6);   // b*N + j
    int lane = threadIdx.x & 63;
    int h  = lane >> 3;
    int d8 = (lane & 7) * 8;
    int b  = bj >> 14;

    float rx = ref[(size_t)bj * 2 + 0];
    float ry = ref[(size_t)bj * 2 + 1];
    uint4 offv = *(const uint4*)(off + (size_t)bj * 64 + h * 8);
    uint2 awv  = *(const uint2*)(aw + (size_t)bj * 32 + h * 4);

    float l0 = bf2f((u16)(awv.x & 0xffff)), l1 = bf2f((u16)(awv.x >> 16));
    float l2 = bf2f((u16)(awv.y & 0xffff)), l3 = bf2f((u16)(awv.y >> 16));
    float mx = fmaxf(fmaxf(l0, l1), fmaxf(l2, l3));
    float e[4];
    e[0] = expf(l0 - mx); e[1] = expf(l1 - mx);
    e[2] = expf(l2 - mx); e[3] = expf(l3 - mx);
    float inv_es = 1.0f / (e[0] + e[1] + e[2] + e[3]);

    const u16* vb = v + (size_t)b * NDIM * CDIM + h * HEAD_DIM + d8;
    float acc[8] = {0.f, 0.f, 0.f, 0.f, 0.f, 0.f, 0.f, 0.f};
    unsigned ow[4] = {offv.x, offv.y, offv.z, offv.w};

#pragma unroll
    for (int p = 0; p < NPTS; ++p) {
        float ox = bf2f((u16)(ow[p] & 0xffff));
        float oy = bf2f((u16)(ow[p] >> 16));
        float X = rx * (float)WDIM + ox - 0.5f;
        float Y = ry * (float)HDIM + oy - 0.5f;
        float x0f = floorf(X), y0f = floorf(Y);
        float wx = X - x0f, wy = Y - y0f;
        int x0 = (int)x0f, y0 = (int)y0f;
        float ep = e[p];
#pragma unroll
        for (int cy = 0; cy < 2; ++cy) {
            int yy = y0 + cy;
            float wyc = cy ? wy : (1.0f - wy);
            int yin = (yy >= 0) & (yy < HDIM);
            int yc = min(max(yy, 0), HDIM - 1);
#pragma unroll
            for (int cx = 0; cx < 2; ++cx) {
                int xx = x0 + cx;
                float wxc = cx ? wx : (1.0f - wx);
                int xin = (xx >= 0) & (xx < WDIM);
                int xc = min(max(xx, 0), WDIM - 1);
                float wgt = ep * wyc * wxc * (float)(yin & xin);
                uint4 vv = *(const uint4*)(vb + (size_t)(yc * WDIM + xc) * CDIM);
                acc[0] += wgt * bf2f((u16)(vv.x & 0xffff));
                acc[1] += wgt * bf2f((u16)(vv.x >> 16));
                acc[2] += wgt * bf2f((u16)(vv.y & 0xffff));
                acc[3] += wgt * bf2f((u16)(vv.y >> 16));
                acc[4] += wgt * bf2f((u16)(vv.z & 0xffff));
                acc[5] += wgt * bf2f((u16)(vv.z >> 16));
                acc[6] += wgt * bf2f((u16)(vv.w & 0xffff));
                acc[7] += wgt * bf2f((u16)(vv.w >> 16));
            }
        }
    }
    uint4 r;
    r.x = (unsigned)f2bf(acc[0] * inv_es) | ((unsigned)f2bf(acc[1] * inv_es) << 16);
    r.y = (unsigned)f2bf(acc[2] * inv_es) | ((unsigned)f2bf(acc[3] * inv_es) << 16);
    r.z = (unsigned)f2bf(acc[4] * inv_es) | ((unsigned)f2bf(acc[5] * inv_es) << 16);
    r.w = (unsigned)f2bf(acc[6] * inv_es) | ((unsigned)f2bf(acc[7] * inv_es) << 16);
    *(uint4*)(out + (size_t)bj * CDIM + h * HEAD_DIM + d8) = r;
}

// ---------------------------------------------------------------------------
// launcher
// ---------------------------------------------------------------------------
extern "C" void kernel_launch(void* const* d_in, const int* in_sizes, int n_in,
                              void* d_out, int out_size, void* d_ws, size_t ws_size,
                              hipStream_t stream)
{
    const float* bev   = (const float*)d_in[0];
    const float* lidar = (const float*)d_in[1];
    const float* Wv    = (const float*)d_in[2];
    const float* bv    = (const float*)d_in[3];
    const float* Woff  = (const float*)d_in[4];
    const float* boff  = (const float*)d_in[5];
    const float* Waw   = (const float*)d_in[6];
    const float* baw   = (const float*)d_in[7];
    const float* Wout  = (const float*)d_in[8];
    const float* bout  = (const float*)d_in[9];
    const float* ln1g  = (const float*)d_in[10];
    const float* ln1b  = (const float*)d_in[11];
    const float* W1    = (const float*)d_in[12];
    const float* W2    = (const float*)d_in[13];
    const float* ln2g  = (const float*)d_in[14];
    const float* ln2b  = (const float*)d_in[15];
    const float* peW1  = (const float*)d_in[16];
    const float* peg   = (const float*)d_in[17];
    const float* peb   = (const float*)d_in[18];
    const float* pem   = (const float*)d_in[19];
    const float* pev   = (const float*)d_in[20];
    const float* peW2  = (const float*)d_in[21];

    const size_t NC = (size_t)BN_TOT * CDIM;    // 16,777,216
    const size_t WSZ = 512 * 512;               // one square weight

    char* base = (char*)d_ws;
    u16* q      = (u16*)base;                           // NC bf16 (residual stream)
    u16* actA   = (u16*)(base + NC * 2);                // NC bf16 (v / h / pe-hidden)
    u16* actB   = (u16*)(base + NC * 4);                // NC bf16 (x / sampled)
    u16* wt     = (u16*)(base + NC * 6);                // 25 x 512x512 bf16
    u16* wtv    = wt;                                   // [6]
    u16* wtout  = wt + 6 * WSZ;                         // [6]
    u16* wt1    = wt + 12 * WSZ;                        // [6]
    u16* wt2    = wt + 18 * WSZ;                        // [6]
    u16* wtpe   = wt + 24 * WSZ;                        // [1]
    u16* offawt = wt + 25 * WSZ;                        // 6 x 96x512 bf16
    u16* offb   = offawt + 6 * 96 * 512;                // BN x 64 bf16
    u16* awb    = offb + (size_t)BN_TOT * 64;           // BN x 32 bf16
    float* refb = (float*)(awb + (size_t)BN_TOT * 32);  // BN x 2 fp32
    int* mask   = (int*)(refb + (size_t)BN_TOT * 2);
    int* order  = mask + BN_TOT;
    int* nvalid = order + BN_TOT;

    // d_out doubles as scratch until final scatter:
    u16* qpos_bf = (u16*)d_out;                         // NC bf16 (first half)
    u16* featT   = (u16*)d_out + NC;                    // NC bf16 (second half)

    dim3 blk328(32, 8);
    dim3 gemm_grid(4, 256);        // 128x128 tiles
    dim3 offaw_grid(1, 256);
    int  ln_grid = BN_TOT / 128;   // 256 blocks of 128 rows

    // voxelize
    mask_kernel<<<BN_TOT / 256, 256, 0, stream>>>(lidar, mask);
    order_kernel<<<BDIM, 256, 0, stream>>>(mask, order, nvalid);
    ref_kernel<<<BN_TOT / 256, 256, 0, stream>>>(order, nvalid, refb);
    pack_q_kernel<<<dim3(NDIM / 32, CDIM / 32, BDIM), blk328, 0, stream>>>(lidar, order, nvalid, q);
    bev_conv_kernel<<<dim3(NDIM / 32, CDIM / 32, BDIM), blk328, 0, stream>>>(bev, featT);

    // hoisted weight conversions (all layers at once)
    tconv_b_kernel<<<dim3(16, 16, 6), blk328, 0, stream>>>(Wv,   wtv);
    tconv_b_kernel<<<dim3(16, 16, 6), blk328, 0, stream>>>(Wout, wtout);
    tconv_b_kernel<<<dim3(16, 16, 6), blk328, 0, stream>>>(W1,   wt1);
    tconv_b_kernel<<<dim3(16, 16, 6), blk328, 0, stream>>>(W2,   wt2);
    tconv_b_kernel<<<dim3(16, 16, 1), blk328, 0, stream>>>(peW2, wtpe);
    tconv_offaw_b_kernel<<<dim3(16, 3, 6), blk328, 0, stream>>>(Woff, Waw, offawt);

    // positional embedding: qpos_bf = relu(BN(ref@peW1)) @ peW2
    pe_hidden_kernel<<<BN_TOT, 128, 0, stream>>>(refb, peW1, peg, peb, pem, pev, actA);
    gemm_bf16<<<gemm_grid, 256, 0, stream>>>(actA, wtpe, nullptr, qpos_bf, 0);

    // x0 = q0 + qpos -> actB
    add_bf_kernel<<<(unsigned)(NC / 8 / 256), 256, 0, stream>>>(q, qpos_bf, actB);

    for (int i = 0; i < LNUM; ++i) {
        // off/aw = x @ [Woff|Waw] + bias   (x lives in actB)
        gemm_offaw<<<offaw_grid, 256, 0, stream>>>(actB, offawt + (size_t)i * 96 * 512,
                                                   boff + i * 64, baw + i * 32, offb, awb);
        // v = featT @ Wv + bv -> actA
        gemm_bf16<<<gemm_grid, 256, 0, stream>>>(featT, wtv + (size_t)i * WSZ,
                                                 bv + i * CDIM, actA, 0);
        // sampled -> actB (x dead after offaw)
        sample_kernel<<<BN_TOT / 4, 256, 0, stream>>>(refb, offb, awb, actA, actB);
        // q = LN1(sampled @ Wout + bout + q)
        gemm_ln<<<ln_grid, 512, 0, stream>>>(actB, wtout + (size_t)i * WSZ, bout + i * CDIM,
                                             q, ln1g + i * CDIM, ln1b + i * CDIM,
                                             q, nullptr, nullptr);
        // h = relu(q @ W1) -> actA
        gemm_bf16<<<gemm_grid, 256, 0, stream>>>(q, wt1 + (size_t)i * WSZ, nullptr, actA, 1);
        // q = LN2(h @ W2 + q); x_{i+1} = q + qpos -> actB (skip on last layer)
        gemm_ln<<<ln_grid, 512, 0, stream>>>(actA, wt2 + (size_t)i * WSZ, nullptr,
                                             q, ln2g + i * CDIM, ln2b + i * CDIM,
                                             q, qpos_bf,
                                             (i < LNUM - 1) ? actB : nullptr);
    }

    // scatter back to dense (B, C, H, W) — overwrites all of d_out
    scatter_kernel<<<dim3(NDIM / 32, CDIM / 32, BDIM), blk328, 0, stream>>>(
        q, order, nvalid, (float*)d_out);
}

// Round 5
// 1850.128 us; speedup vs baseline: 1.0136x; 1.0136x over previous
//
#include <hip/hip_runtime.h>
#include <cstdint>
#include <cstddef>

// Problem constants
#define BDIM 2
#define CDIM 512
#define HDIM 128
#define WDIM 128
#define NDIM (HDIM * WDIM)        // 16384
#define LNUM 6
#define NHEADS 8
#define HEAD_DIM 64
#define NPTS 4
#define BN_TOT (BDIM * NDIM)      // 32768

typedef unsigned short u16;
typedef __attribute__((ext_vector_type(8))) short bf16x8;   // 8 bf16 = 4 VGPRs
typedef __attribute__((ext_vector_type(4))) float f32x4;    // MFMA accum

__device__ __forceinline__ u16 f2bf(float x) {              // RNE fp32->bf16
    unsigned u = __float_as_uint(x);
    u += 0x7fffu + ((u >> 16) & 1u);
    return (u16)(u >> 16);
}
__device__ __forceinline__ float bf2f(u16 h) {
    return __uint_as_float(((unsigned)h) << 16);
}

__device__ __forceinline__ void load_lds16(const void* g, void* l) {
    // async global->LDS, 16B/lane; LDS dest = wave-uniform base + lane*16
    __builtin_amdgcn_global_load_lds(
        (const __attribute__((address_space(1))) void*)g,
        (__attribute__((address_space(3))) void*)l, 16, 0, 0);
}

// counted vmem waits (literal-only in asm string)
__device__ __forceinline__ void wait_vm8() { asm volatile("s_waitcnt vmcnt(8)" ::: "memory"); }
__device__ __forceinline__ void wait_vm4() { asm volatile("s_waitcnt vmcnt(4)" ::: "memory"); }
__device__ __forceinline__ void wait_vm0() { asm volatile("s_waitcnt vmcnt(0)" ::: "memory"); }
__device__ __forceinline__ void sbar()  { __builtin_amdgcn_s_barrier(); }
__device__ __forceinline__ void spin()  { __builtin_amdgcn_sched_barrier(0); }

// ---------------------------------------------------------------------------
// voxelization: mask / order / ref / pack_q(bf16)
// ---------------------------------------------------------------------------
__global__ void mask_kernel(const float* __restrict__ lidar, int* __restrict__ mask)
{
    int idx = blockIdx.x * blockDim.x + threadIdx.x;
    if (idx >= BN_TOT) return;
    int b = idx / NDIM;
    int n = idx - b * NDIM;
    const float* p = lidar + (size_t)b * CDIM * NDIM + n;
    int ok = 1;
#pragma unroll 8
    for (int c = 0; c < CDIM; ++c)
        ok &= (p[(size_t)c * NDIM] != 0.0f);
    mask[idx] = ok;
}

__global__ void order_kernel(const int* __restrict__ mask, int* __restrict__ order,
                             int* __restrict__ nvalid)
{
    int b = blockIdx.x;
    const int* m = mask + b * NDIM;
    int* ord = order + b * NDIM;
    __shared__ int part[256];
    __shared__ int totalValid;
    int t = threadIdx.x;
    const int CHUNK = NDIM / 256;
    int base = t * CHUNK;
    int cnt = 0;
    for (int i = 0; i < CHUNK; ++i) cnt += m[base + i];
    part[t] = cnt;
    __syncthreads();
    for (int s = 1; s < 256; s <<= 1) {
        int v = (t >= s) ? part[t - s] : 0;
        __syncthreads();
        part[t] += v;
        __syncthreads();
    }
    if (t == 255) { totalValid = part[255]; nvalid[b] = part[255]; }
    __syncthreads();
    int validBefore = (t == 0) ? 0 : part[t - 1];
    int nv = totalValid;
    for (int i = 0; i < CHUNK; ++i) {
        int n = base + i;
        if (m[n]) { ord[validBefore] = n; validBefore++; }
        else      { int invBefore = n - validBefore; ord[nv + invBefore] = n; }
    }
}

__global__ void ref_kernel(const int* __restrict__ order, const int* __restrict__ nvalid,
                           float* __restrict__ ref)
{
    int idx = blockIdx.x * blockDim.x + threadIdx.x;
    if (idx >= BN_TOT) return;
    int b = idx / NDIM;
    int j = idx - b * NDIM;
    int n = order[idx];
    float flag = (j < nvalid[b]) ? 1.0f : 0.0f;
    int hh = n / WDIM;
    int ww = n - hh * WDIM;
    ref[(size_t)idx * 2 + 0] = ((float)ww / (float)WDIM) * flag;
    ref[(size_t)idx * 2 + 1] = ((float)hh / (float)HDIM) * flag;
}

__global__ void pack_q_kernel(const float* __restrict__ lidar, const int* __restrict__ order,
                              const int* __restrict__ nvalid, u16* __restrict__ q)
{
    __shared__ float tile[32][33];
    __shared__ int ord_s[32];
    int b  = blockIdx.z;
    int j0 = blockIdx.x * 32;
    int c0 = blockIdx.y * 32;
    int tx = threadIdx.x, ty = threadIdx.y;
    if (ty == 0) ord_s[tx] = order[b * NDIM + j0 + tx];
    __syncthreads();
    const float* src = lidar + (size_t)b * CDIM * NDIM;
#pragma unroll
    for (int k = 0; k < 4; ++k) {
        int cl = ty * 4 + k;
        tile[cl][tx] = src[(size_t)(c0 + cl) * NDIM + ord_s[tx]];
    }
    __syncthreads();
    int nv = nvalid[b];
#pragma unroll
    for (int k = 0; k < 4; ++k) {
        int jl = ty * 4 + k;
        int j = j0 + jl;
        float f = (j < nv) ? 1.0f : 0.0f;
        q[((size_t)b * NDIM + j) * CDIM + c0 + tx] = f2bf(tile[tx][jl] * f);
    }
}

// final scatter: out[b,c,order[j]] = q(bf16)[b,j,c] * valid  (fp32 out)
__global__ void scatter_kernel(const u16* __restrict__ q, const int* __restrict__ order,
                               const int* __restrict__ nvalid, float* __restrict__ out)
{
    __shared__ float tile[32][33];
    __shared__ int ord_s[32];
    int b  = blockIdx.z;
    int j0 = blockIdx.x * 32;
    int c0 = blockIdx.y * 32;
    int tx = threadIdx.x, ty = threadIdx.y;
    if (ty == 0) ord_s[tx] = order[b * NDIM + j0 + tx];
    __syncthreads();
    int nv = nvalid[b];
#pragma unroll
    for (int k = 0; k < 4; ++k) {
        int jl = ty * 4 + k;
        int j = j0 + jl;
        float f = (j < nv) ? 1.0f : 0.0f;
        tile[jl][tx] = bf2f(q[((size_t)b * NDIM + j) * CDIM + c0 + tx]) * f;
    }
    __syncthreads();
    float* dst = out + (size_t)b * CDIM * NDIM;
#pragma unroll
    for (int k = 0; k < 4; ++k) {
        int cl = ty * 4 + k;
        dst[(size_t)(c0 + cl) * NDIM + ord_s[tx]] = tile[tx][cl];
    }
}

// ---------------------------------------------------------------------------
// batched weight transpose-convert: src fp32 [z][512][512] -> dst bf16 [z][N][K]
// ---------------------------------------------------------------------------
__global__ void tconv_b_kernel(const float* __restrict__ src0, u16* __restrict__ dst0)
{
    __shared__ float t[32][33];
    int z = blockIdx.z;
    const float* src = src0 + (size_t)z * 512 * 512;
    u16* dst = dst0 + (size_t)z * 512 * 512;
    int k0 = blockIdx.x * 32, n0 = blockIdx.y * 32;
    int tx = threadIdx.x, ty = threadIdx.y;
#pragma unroll
    for (int j = 0; j < 4; ++j) {
        int kl = ty * 4 + j;
        t[kl][tx] = src[(size_t)(k0 + kl) * 512 + n0 + tx];
    }
    __syncthreads();
#pragma unroll
    for (int j = 0; j < 4; ++j) {
        int nl = ty * 4 + j;
        dst[(size_t)(n0 + nl) * 512 + k0 + tx] = f2bf(t[tx][nl]);
    }
}

// batched: Woff [z][512][64] + Waw [z][512][32] -> dst bf16 [z][96][512]
__global__ void tconv_offaw_b_kernel(const float* __restrict__ woff0,
                                     const float* __restrict__ waw0,
                                     u16* __restrict__ dst0)
{
    __shared__ float t[32][33];
    int z = blockIdx.z;
    const float* woff = woff0 + (size_t)z * 512 * 64;
    const float* waw  = waw0 + (size_t)z * 512 * 32;
    u16* dst = dst0 + (size_t)z * 96 * 512;
    int k0 = blockIdx.x * 32, n0 = blockIdx.y * 32;
    int tx = threadIdx.x, ty = threadIdx.y;
#pragma unroll
    for (int j = 0; j < 4; ++j) {
        int kl = ty * 4 + j;
        int n = n0 + tx;
        float v = (n < 64) ? woff[(size_t)(k0 + kl) * 64 + n]
                           : waw[(size_t)(k0 + kl) * 32 + (n - 64)];
        t[kl][tx] = v;
    }
    __syncthreads();
#pragma unroll
    for (int j = 0; j < 4; ++j) {
        int nl = ty * 4 + j;
        dst[(size_t)(n0 + nl) * 512 + k0 + tx] = f2bf(t[tx][nl]);
    }
}

// bev (B,C,N) fp32 -> featT (B,N,C) bf16
__global__ void bev_conv_kernel(const float* __restrict__ bev, u16* __restrict__ dst)
{
    __shared__ float t[32][33];
    int b  = blockIdx.z;
    int n0 = blockIdx.x * 32;
    int c0 = blockIdx.y * 32;
    int tx = threadIdx.x, ty = threadIdx.y;
    const float* src = bev + (size_t)b * CDIM * NDIM;
#pragma unroll
    for (int j = 0; j < 4; ++j) {
        int cl = ty * 4 + j;
        t[cl][tx] = src[(size_t)(c0 + cl) * NDIM + n0 + tx];
    }
    __syncthreads();
#pragma unroll
    for (int j = 0; j < 4; ++j) {
        int nl = ty * 4 + j;
        dst[((size_t)b * NDIM + n0 + nl) * CDIM + c0 + tx] = f2bf(t[tx][nl]);
    }
}

// ---------------------------------------------------------------------------
// PE hidden: h = relu(BN(ref @ pe_W1))  -> bf16
// ---------------------------------------------------------------------------
__global__ void pe_hidden_kernel(const float* __restrict__ ref, const float* __restrict__ W1,
                                 const float* __restrict__ g, const float* __restrict__ bb,
                                 const float* __restrict__ m, const float* __restrict__ v,
                                 u16* __restrict__ out)
{
    int row = blockIdx.x;
    float r0 = ref[(size_t)row * 2 + 0];
    float r1 = ref[(size_t)row * 2 + 1];
    for (int c = threadIdx.x; c < CDIM; c += blockDim.x) {
        float pe = r0 * W1[c] + r1 * W1[CDIM + c];
        pe = (pe - m[c]) * rsqrtf(v[c] + 1e-5f) * g[c] + bb[c];
        out[(size_t)row * CDIM + c] = f2bf(fmaxf(pe, 0.0f));
    }
}

// ---------------------------------------------------------------------------
// x = q(bf16) + qpos(bf16) -> bf16 ; 8 elements/thread
// ---------------------------------------------------------------------------
__global__ void add_bf_kernel(const u16* __restrict__ q, const u16* __restrict__ qpos,
                              u16* __restrict__ x)
{
    size_t i = (size_t)blockIdx.x * blockDim.x + threadIdx.x;  // 8-el group
    uint4 qa = ((const uint4*)q)[i];
    uint4 pv = ((const uint4*)qpos)[i];
    unsigned qw[4] = {qa.x, qa.y, qa.z, qa.w};
    unsigned pw[4] = {pv.x, pv.y, pv.z, pv.w};
    unsigned rw[4];
#pragma unroll
    for (int k = 0; k < 4; ++k) {
        float a0 = bf2f((u16)(qw[k] & 0xffff)), a1 = bf2f((u16)(qw[k] >> 16));
        float p0 = bf2f((u16)(pw[k] & 0xffff)), p1 = bf2f((u16)(pw[k] >> 16));
        rw[k] = (unsigned)f2bf(a0 + p0) | ((unsigned)f2bf(a1 + p1) << 16);
    }
    uint4 r; r.x = rw[0]; r.y = rw[1]; r.z = rw[2]; r.w = rw[3];
    ((uint4*)x)[i] = r;
}

// ---------------------------------------------------------------------------
// MFMA bf16 GEMM. 128x128 tile, BK=32, 4 waves, grid (4, 256) = 1024 blocks.
// v4 schedule: non-redundant wave staging, two raw barriers per K-step,
// counted vmcnt(4) so next-tile DMAs stay in flight across the barrier.
// ---------------------------------------------------------------------------
__global__ __launch_bounds__(256) void gemm_bf16(
    const u16* __restrict__ A, const u16* __restrict__ Bt,
    const float* __restrict__ bias, u16* __restrict__ outB, int relu)
{
    __shared__ u16 As[2][128 * 32];
    __shared__ u16 Bs[2][128 * 32];
    int tid = threadIdx.x;
    int wave = tid >> 6, lane = tid & 63;
    int wr = wave >> 1, wc = wave & 1;
    int quad = lane >> 4, l15 = lane & 15;
    int bm = blockIdx.y * 128, bn = blockIdx.x * 128;

    f32x4 acc[4][4];
#pragma unroll
    for (int i = 0; i < 4; ++i)
#pragma unroll
        for (int j = 0; j < 4; ++j) { f32x4 z = {0.f, 0.f, 0.f, 0.f}; acc[i][j] = z; }

    int ch0 = wave, ch1 = wave + 4;
    const u16* Ag0 = A  + (size_t)(bm + ch0 * 16 + (lane >> 2)) * 512 + (lane & 3) * 8;
    const u16* Ag1 = A  + (size_t)(bm + ch1 * 16 + (lane >> 2)) * 512 + (lane & 3) * 8;
    const u16* Bg0 = Bt + (size_t)(bn + ch0 * 16 + (lane >> 2)) * 512 + (lane & 3) * 8;
    const u16* Bg1 = Bt + (size_t)(bn + ch1 * 16 + (lane >> 2)) * 512 + (lane & 3) * 8;

    load_lds16(Ag0, &As[0][ch0 * 512]);
    load_lds16(Ag1, &As[0][ch1 * 512]);
    load_lds16(Bg0, &Bs[0][ch0 * 512]);
    load_lds16(Bg1, &Bs[0][ch1 * 512]);

    for (int it = 0; it < 16; ++it) {
        sbar();  spin();                    // prev readers of nxt done
        int cur = it & 1, nxt = cur ^ 1;
        if (it < 15) {
            int kn = (it + 1) * 32;
            load_lds16(Ag0 + kn, &As[nxt][ch0 * 512]);
            load_lds16(Ag1 + kn, &As[nxt][ch1 * 512]);
            load_lds16(Bg0 + kn, &Bs[nxt][ch0 * 512]);
            load_lds16(Bg1 + kn, &Bs[nxt][ch1 * 512]);
            wait_vm4();                     // own cur loads landed; nxt in flight
        } else {
            wait_vm0();
        }
        sbar();  spin();                    // everyone's cur loads landed
        bf16x8 av[4], bv[4];
#pragma unroll
        for (int mi = 0; mi < 4; ++mi)
            av[mi] = *(const bf16x8*)&As[cur][(wr * 64 + mi * 16 + l15) * 32 + quad * 8];
#pragma unroll
        for (int ni = 0; ni < 4; ++ni)
            bv[ni] = *(const bf16x8*)&Bs[cur][(wc * 64 + ni * 16 + l15) * 32 + quad * 8];
#pragma unroll
        for (int mi = 0; mi < 4; ++mi)
#pragma unroll
            for (int ni = 0; ni < 4; ++ni)
                acc[mi][ni] = __builtin_amdgcn_mfma_f32_16x16x32_bf16(
                    av[mi], bv[ni], acc[mi][ni], 0, 0, 0);
    }

    int rowb = bm + wr * 64;
    int colb = bn + wc * 64;
#pragma unroll
    for (int mi = 0; mi < 4; ++mi) {
#pragma unroll
        for (int ni = 0; ni < 4; ++ni) {
            int col = colb + ni * 16 + l15;
            float bi = bias ? bias[col] : 0.0f;
#pragma unroll
            for (int r = 0; r < 4; ++r) {
                int row = rowb + mi * 16 + quad * 4 + r;
                float val = acc[mi][ni][r] + bi;
                if (relu) val = fmaxf(val, 0.0f);
                outB[(size_t)row * 512 + col] = f2bf(val);
            }
        }
    }
}

// ---------------------------------------------------------------------------
// gemm_residf: gemm_bf16 v4 structure; epilogue writes Y = acc + bias + resid
// in **fp32** (no rounding before LN — exact fused-kernel math). Operates on a
// 16K-row chunk: A/resid pointers pre-offset by the launcher, outY chunk-local.
// Grid (4, 128) = 512 blocks, 2/CU.
// ---------------------------------------------------------------------------
__global__ __launch_bounds__(256) void gemm_residf(
    const u16* __restrict__ A, const u16* __restrict__ Bt,
    const float* __restrict__ bias, const u16* __restrict__ resid,
    float* __restrict__ outY)
{
    __shared__ u16 As[2][128 * 32];
    __shared__ u16 Bs[2][128 * 32];
    int tid = threadIdx.x;
    int wave = tid >> 6, lane = tid & 63;
    int wr = wave >> 1, wc = wave & 1;
    int quad = lane >> 4, l15 = lane & 15;
    int bm = blockIdx.y * 128, bn = blockIdx.x * 128;

    f32x4 acc[4][4];
#pragma unroll
    for (int i = 0; i < 4; ++i)
#pragma unroll
        for (int j = 0; j < 4; ++j) { f32x4 z = {0.f, 0.f, 0.f, 0.f}; acc[i][j] = z; }

    int ch0 = wave, ch1 = wave + 4;
    const u16* Ag0 = A  + (size_t)(bm + ch0 * 16 + (lane >> 2)) * 512 + (lane & 3) * 8;
    const u16* Ag1 = A  + (size_t)(bm + ch1 * 16 + (lane >> 2)) * 512 + (lane & 3) * 8;
    const u16* Bg0 = Bt + (size_t)(bn + ch0 * 16 + (lane >> 2)) * 512 + (lane & 3) * 8;
    const u16* Bg1 = Bt + (size_t)(bn + ch1 * 16 + (lane >> 2)) * 512 + (lane & 3) * 8;

    load_lds16(Ag0, &As[0][ch0 * 512]);
    load_lds16(Ag1, &As[0][ch1 * 512]);
    load_lds16(Bg0, &Bs[0][ch0 * 512]);
    load_lds16(Bg1, &Bs[0][ch1 * 512]);

    for (int it = 0; it < 16; ++it) {
        sbar();  spin();
        int cur = it & 1, nxt = cur ^ 1;
        if (it < 15) {
            int kn = (it + 1) * 32;
            load_lds16(Ag0 + kn, &As[nxt][ch0 * 512]);
            load_lds16(Ag1 + kn, &As[nxt][ch1 * 512]);
            load_lds16(Bg0 + kn, &Bs[nxt][ch0 * 512]);
            load_lds16(Bg1 + kn, &Bs[nxt][ch1 * 512]);
            wait_vm4();
        } else {
            wait_vm0();
        }
        sbar();  spin();
        bf16x8 av[4], bv[4];
#pragma unroll
        for (int mi = 0; mi < 4; ++mi)
            av[mi] = *(const bf16x8*)&As[cur][(wr * 64 + mi * 16 + l15) * 32 + quad * 8];
#pragma unroll
        for (int ni = 0; ni < 4; ++ni)
            bv[ni] = *(const bf16x8*)&Bs[cur][(wc * 64 + ni * 16 + l15) * 32 + quad * 8];
#pragma unroll
        for (int mi = 0; mi < 4; ++mi)
#pragma unroll
            for (int ni = 0; ni < 4; ++ni)
                acc[mi][ni] = __builtin_amdgcn_mfma_f32_16x16x32_bf16(
                    av[mi], bv[ni], acc[mi][ni], 0, 0, 0);
    }

    int rowb = bm + wr * 64;
    int colb = bn + wc * 64;
#pragma unroll
    for (int mi = 0; mi < 4; ++mi) {
#pragma unroll
        for (int ni = 0; ni < 4; ++ni) {
            int col = colb + ni * 16 + l15;
            float bi = bias ? bias[col] : 0.0f;
#pragma unroll
            for (int r = 0; r < 4; ++r) {
                int row = rowb + mi * 16 + quad * 4 + r;
                size_t off = (size_t)row * 512 + col;
                outY[off] = acc[mi][ni][r] + bi + bf2f(resid[off]);
            }
        }
    }
}

// ---------------------------------------------------------------------------
// ln_f: per-row LayerNorm over 512 cols of fp32 Y (chunk-local). One wave per
// row, lane holds 8 cols. fp32 stats + fp32 normalize, single bf16 rounding at
// the output — same math as the verified fused epilogue.
// ---------------------------------------------------------------------------
__global__ __launch_bounds__(256) void ln_f(
    const float* __restrict__ Y, const float* __restrict__ g,
    const float* __restrict__ bta, u16* __restrict__ outQ)
{
    int row  = blockIdx.x * 4 + (threadIdx.x >> 6);
    int lane = threadIdx.x & 63;
    size_t base = (size_t)row * CDIM + lane * 8;

    float4 y0 = *(const float4*)(Y + base);
    float4 y1 = *(const float4*)(Y + base + 4);
    float v[8] = {y0.x, y0.y, y0.z, y0.w, y1.x, y1.y, y1.z, y1.w};

    float s = 0.f, s2 = 0.f;
#pragma unroll
    for (int j = 0; j < 8; ++j) { s += v[j]; s2 += v[j] * v[j]; }
#pragma unroll
    for (int m = 1; m < 64; m <<= 1) {
        s  += __shfl_xor(s, m, 64);
        s2 += __shfl_xor(s2, m, 64);
    }
    float mu = s * (1.0f / 512.0f);
    float var = s2 * (1.0f / 512.0f) - mu * mu;
    float iv = rsqrtf(var + 1e-5f);

    int c0 = lane * 8;
    float4 g0 = *(const float4*)(g + c0);
    float4 g1 = *(const float4*)(g + c0 + 4);
    float4 b0 = *(const float4*)(bta + c0);
    float4 b1 = *(const float4*)(bta + c0 + 4);
    float gl[8] = {g0.x, g0.y, g0.z, g0.w, g1.x, g1.y, g1.z, g1.w};
    float bl[8] = {b0.x, b0.y, b0.z, b0.w, b1.x, b1.y, b1.z, b1.w};

    unsigned qw[4];
#pragma unroll
    for (int k = 0; k < 4; ++k) {
        float a = (v[2 * k]     - mu) * iv * gl[2 * k]     + bl[2 * k];
        float b = (v[2 * k + 1] - mu) * iv * gl[2 * k + 1] + bl[2 * k + 1];
        qw[k] = (unsigned)f2bf(a) | ((unsigned)f2bf(b) << 16);
    }
    uint4 qo; qo.x = qw[0]; qo.y = qw[1]; qo.z = qw[2]; qo.w = qw[3];
    *(uint4*)(outQ + base) = qo;
}

// ---------------------------------------------------------------------------
// fused off+aw GEMM (v3 schedule, kept): A @ OffAwT[96][512] -> offb/awb
// ---------------------------------------------------------------------------
__global__ __launch_bounds__(256) void gemm_offaw(
    const u16* __restrict__ A, const u16* __restrict__ Bt,
    const float* __restrict__ boff, const float* __restrict__ baw,
    u16* __restrict__ offb, u16* __restrict__ awb)
{
    __shared__ u16 As[2][128 * 32];
    __shared__ u16 Bs[2][128 * 32];
    int tid = threadIdx.x;
    int wave = tid >> 6, lane = tid & 63;
    int wr = wave >> 1, wc = wave & 1;
    int quad = lane >> 4, l15 = lane & 15;
    int bm = blockIdx.y * 128;

    f32x4 acc[4][4];
#pragma unroll
    for (int i = 0; i < 4; ++i)
#pragma unroll
        for (int j = 0; j < 4; ++j) { f32x4 z = {0.f, 0.f, 0.f, 0.f}; acc[i][j] = z; }

    // wave-local staging; B rows clamped at 95 (cols >=96 are discarded)
    const u16* Ag[4];
    const u16* Bg[4];
#pragma unroll
    for (int s = 0; s < 4; ++s) {
        Ag[s] = A + (size_t)(bm + wr * 64 + s * 16 + (lane >> 2)) * 512 + (lane & 3) * 8;
        int br = wc * 64 + s * 16 + (lane >> 2);
        if (br > 95) br = 95;
        Bg[s] = Bt + (size_t)br * 512 + (lane & 3) * 8;
    }

#pragma unroll
    for (int s = 0; s < 4; ++s) {
        load_lds16(Ag[s], &As[0][(wr * 4 + s) * 512]);
        load_lds16(Bg[s], &Bs[0][(wc * 4 + s) * 512]);
    }

    for (int it = 0; it < 16; ++it) {
        sbar();
        int cur = it & 1, nxt = cur ^ 1;
        if (it < 15) {
            int kn = (it + 1) * 32;
#pragma unroll
            for (int s = 0; s < 4; ++s) {
                load_lds16(Ag[s] + kn, &As[nxt][(wr * 4 + s) * 512]);
                load_lds16(Bg[s] + kn, &Bs[nxt][(wc * 4 + s) * 512]);
            }
            wait_vm8();
        } else {
            wait_vm0();
        }
        bf16x8 av[4], bv[4];
#pragma unroll
        for (int mi = 0; mi < 4; ++mi)
            av[mi] = *(const bf16x8*)&As[cur][(wr * 64 + mi * 16 + l15) * 32 + quad * 8];
#pragma unroll
        for (int ni = 0; ni < 4; ++ni)
            bv[ni] = *(const bf16x8*)&Bs[cur][(wc * 64 + ni * 16 + l15) * 32 + quad * 8];
#pragma unroll
        for (int mi = 0; mi < 4; ++mi)
#pragma unroll
            for (int ni = 0; ni < 4; ++ni)
                acc[mi][ni] = __builtin_amdgcn_mfma_f32_16x16x32_bf16(
                    av[mi], bv[ni], acc[mi][ni], 0, 0, 0);
    }

    int rowb = bm + wr * 64;
#pragma unroll
    for (int mi = 0; mi < 4; ++mi) {
#pragma unroll
        for (int ni = 0; ni < 4; ++ni) {
            int col = wc * 64 + ni * 16 + l15;
            if (col < 96) {
                float bi = (col < 64) ? boff[col] : baw[col - 64];
#pragma unroll
                for (int r = 0; r < 4; ++r) {
                    int row = rowb + mi * 16 + quad * 4 + r;
                    float val = acc[mi][ni][r] + bi;
                    if (col < 64) offb[(size_t)row * 64 + col] = f2bf(val);
                    else          awb[(size_t)row * 32 + (col - 64)] = f2bf(val);
                }
            }
        }
    }
}

// ---------------------------------------------------------------------------
// deformable sampling: one wave per (b,j); lane = (head, 8 channels)
// ---------------------------------------------------------------------------
__global__ __launch_bounds__(256) void sample_kernel(
    const float* __restrict__ ref, const u16* __restrict__ off,
    const u16* __restrict__ aw, const u16* __restrict__ v,
    u16* __restrict__ out)
{
    int bj = blockIdx.x * 4 + (threadIdx.x >> 6);   // b*N + j
    int lane = threadIdx.x & 63;
    int h  = lane >> 3;
    int d8 = (lane & 7) * 8;
    int b  = bj >> 14;

    float rx = ref[(size_t)bj * 2 + 0];
    float ry = ref[(size_t)bj * 2 + 1];
    uint4 offv = *(const uint4*)(off + (size_t)bj * 64 + h * 8);
    uint2 awv  = *(const uint2*)(aw + (size_t)bj * 32 + h * 4);

    float l0 = bf2f((u16)(awv.x & 0xffff)), l1 = bf2f((u16)(awv.x >> 16));
    float l2 = bf2f((u16)(awv.y & 0xffff)), l3 = bf2f((u16)(awv.y >> 16));
    float mx = fmaxf(fmaxf(l0, l1), fmaxf(l2, l3));
    float e[4];
    e[0] = expf(l0 - mx); e[1] = expf(l1 - mx);
    e[2] = expf(l2 - mx); e[3] = expf(l3 - mx);
    float inv_es = 1.0f / (e[0] + e[1] + e[2] + e[3]);

    const u16* vb = v + (size_t)b * NDIM * CDIM + h * HEAD_DIM + d8;
    float acc[8] = {0.f, 0.f, 0.f, 0.f, 0.f, 0.f, 0.f, 0.f};
    unsigned ow[4] = {offv.x, offv.y, offv.z, offv.w};

#pragma unroll
    for (int p = 0; p < NPTS; ++p) {
        float ox = bf2f((u16)(ow[p] & 0xffff));
        float oy = bf2f((u16)(ow[p] >> 16));
        float X = rx * (float)WDIM + ox - 0.5f;
        float Y = ry * (float)HDIM + oy - 0.5f;
        float x0f = floorf(X), y0f = floorf(Y);
        float wx = X - x0f, wy = Y - y0f;
        int x0 = (int)x0f, y0 = (int)y0f;
        float ep = e[p];
#pragma unroll
        for (int cy = 0; cy < 2; ++cy) {
            int yy = y0 + cy;
            float wyc = cy ? wy : (1.0f - wy);
            int yin = (yy >= 0) & (yy < HDIM);
            int yc = min(max(yy, 0), HDIM - 1);
#pragma unroll
            for (int cx = 0; cx < 2; ++cx) {
                int xx = x0 + cx;
                float wxc = cx ? wx : (1.0f - wx);
                int xin = (xx >= 0) & (xx < WDIM);
                int xc = min(max(xx, 0), WDIM - 1);
                float wgt = ep * wyc * wxc * (float)(yin & xin);
                uint4 vv = *(const uint4*)(vb + (size_t)(yc * WDIM + xc) * CDIM);
                acc[0] += wgt * bf2f((u16)(vv.x & 0xffff));
                acc[1] += wgt * bf2f((u16)(vv.x >> 16));
                acc[2] += wgt * bf2f((u16)(vv.y & 0xffff));
                acc[3] += wgt * bf2f((u16)(vv.y >> 16));
                acc[4] += wgt * bf2f((u16)(vv.z & 0xffff));
                acc[5] += wgt * bf2f((u16)(vv.z >> 16));
                acc[6] += wgt * bf2f((u16)(vv.w & 0xffff));
                acc[7] += wgt * bf2f((u16)(vv.w >> 16));
            }
        }
    }
    uint4 r;
    r.x = (unsigned)f2bf(acc[0] * inv_es) | ((unsigned)f2bf(acc[1] * inv_es) << 16);
    r.y = (unsigned)f2bf(acc[2] * inv_es) | ((unsigned)f2bf(acc[3] * inv_es) << 16);
    r.z = (unsigned)f2bf(acc[4] * inv_es) | ((unsigned)f2bf(acc[5] * inv_es) << 16);
    r.w = (unsigned)f2bf(acc[6] * inv_es) | ((unsigned)f2bf(acc[7] * inv_es) << 16);
    *(uint4*)(out + (size_t)bj * CDIM + h * HEAD_DIM + d8) = r;
}

// ---------------------------------------------------------------------------
// launcher
// ---------------------------------------------------------------------------
extern "C" void kernel_launch(void* const* d_in, const int* in_sizes, int n_in,
                              void* d_out, int out_size, void* d_ws, size_t ws_size,
                              hipStream_t stream)
{
    const float* bev   = (const float*)d_in[0];
    const float* lidar = (const float*)d_in[1];
    const float* Wv    = (const float*)d_in[2];
    const float* bv    = (const float*)d_in[3];
    const float* Woff  = (const float*)d_in[4];
    const float* boff  = (const float*)d_in[5];
    const float* Waw   = (const float*)d_in[6];
    const float* baw   = (const float*)d_in[7];
    const float* Wout  = (const float*)d_in[8];
    const float* bout  = (const float*)d_in[9];
    const float* ln1g  = (const float*)d_in[10];
    const float* ln1b  = (const float*)d_in[11];
    const float* W1    = (const float*)d_in[12];
    const float* W2    = (const float*)d_in[13];
    const float* ln2g  = (const float*)d_in[14];
    const float* ln2b  = (const float*)d_in[15];
    const float* peW1  = (const float*)d_in[16];
    const float* peg   = (const float*)d_in[17];
    const float* peb   = (const float*)d_in[18];
    const float* pem   = (const float*)d_in[19];
    const float* pev   = (const float*)d_in[20];
    const float* pe_W2 = (const float*)d_in[21];

    const size_t NC   = (size_t)BN_TOT * CDIM;   // 16,777,216 elements
    const size_t HALF = NC / 2;                  // 16K rows worth
    const size_t WSZ  = 512 * 512;               // one square weight

    char* base = (char*)d_ws;
    u16* q      = (u16*)base;                           // NC bf16 (residual stream)
    u16* actA   = (u16*)(base + NC * 2);                // NC bf16 (v / h; fp32 Y1 chunk)
    u16* actB   = (u16*)(base + NC * 4);                // NC bf16 (x / sampled; fp32 Y2 chunk)
    float* actAf = (float*)actA;                        // 16K-row fp32 chunk view (32 MB)
    float* actBf = (float*)actB;                        // 16K-row fp32 chunk view (32 MB)
    u16* wt     = (u16*)(base + NC * 6);                // 25 x 512x512 bf16
    u16* wtv    = wt;                                   // [6]
    u16* wtout  = wt + 6 * WSZ;                         // [6]
    u16* wt1    = wt + 12 * WSZ;                        // [6]
    u16* wt2    = wt + 18 * WSZ;                        // [6]
    u16* wtpe   = wt + 24 * WSZ;                        // [1]
    u16* offawt = wt + 25 * WSZ;                        // 6 x 96x512 bf16
    u16* offb   = offawt + 6 * 96 * 512;                // BN x 64 bf16
    u16* awb    = offb + (size_t)BN_TOT * 64;           // BN x 32 bf16
    float* refb = (float*)(awb + (size_t)BN_TOT * 32);  // BN x 2 fp32
    int* mask   = (int*)(refb + (size_t)BN_TOT * 2);
    int* order  = mask + BN_TOT;
    int* nvalid = order + BN_TOT;

    // d_out doubles as scratch until final scatter:
    u16* qpos_bf = (u16*)d_out;                         // NC bf16 (first half)
    u16* featT   = (u16*)d_out + NC;                    // NC bf16 (second half)

    dim3 blk328(32, 8);
    dim3 gemm_grid(4, 256);        // 128x128 tiles, 1024 blocks
    dim3 gemm_half(4, 128);        // 16K-row chunk, 512 blocks
    dim3 offaw_grid(1, 256);
    int  lnf_half = (BN_TOT / 2) / 4;   // 4096 blocks, 4 rows each
    unsigned addb = (unsigned)(NC / 8 / 256);

    // voxelize
    mask_kernel<<<BN_TOT / 256, 256, 0, stream>>>(lidar, mask);
    order_kernel<<<BDIM, 256, 0, stream>>>(mask, order, nvalid);
    ref_kernel<<<BN_TOT / 256, 256, 0, stream>>>(order, nvalid, refb);
    pack_q_kernel<<<dim3(NDIM / 32, CDIM / 32, BDIM), blk328, 0, stream>>>(lidar, order, nvalid, q);
    bev_conv_kernel<<<dim3(NDIM / 32, CDIM / 32, BDIM), blk328, 0, stream>>>(bev, featT);

    // hoisted weight conversions (all layers at once)
    tconv_b_kernel<<<dim3(16, 16, 6), blk328, 0, stream>>>(Wv,   wtv);
    tconv_b_kernel<<<dim3(16, 16, 6), blk328, 0, stream>>>(Wout, wtout);
    tconv_b_kernel<<<dim3(16, 16, 6), blk328, 0, stream>>>(W1,   wt1);
    tconv_b_kernel<<<dim3(16, 16, 6), blk328, 0, stream>>>(W2,   wt2);
    tconv_b_kernel<<<dim3(16, 16, 1), blk328, 0, stream>>>(pe_W2, wtpe);
    tconv_offaw_b_kernel<<<dim3(16, 3, 6), blk328, 0, stream>>>(Woff, Waw, offawt);

    // positional embedding: qpos_bf = relu(BN(ref@peW1)) @ peW2
    pe_hidden_kernel<<<BN_TOT, 128, 0, stream>>>(refb, peW1, peg, peb, pem, pev, actA);
    gemm_bf16<<<gemm_grid, 256, 0, stream>>>(actA, wtpe, nullptr, qpos_bf, 0);

    // x0 = q0 + qpos -> actB
    add_bf_kernel<<<addb, 256, 0, stream>>>(q, qpos_bf, actB);

    for (int i = 0; i < LNUM; ++i) {
        // off/aw = x @ [Woff|Waw] + bias   (x lives in actB)
        gemm_offaw<<<offaw_grid, 256, 0, stream>>>(actB, offawt + (size_t)i * 96 * 512,
                                                   boff + i * 64, baw + i * 32, offb, awb);
        // v = featT @ Wv + bv -> actA
        gemm_bf16<<<gemm_grid, 256, 0, stream>>>(featT, wtv + (size_t)i * WSZ,
                                                 bv + i * CDIM, actA, 0);
        // sampled -> actB (x dead after offaw)
        sample_kernel<<<BN_TOT / 4, 256, 0, stream>>>(refb, offb, awb, actA, actB);
        // Y1 = sampled @ Wout + bout + q  (fp32, 16K-row chunks via actA; v dead)
        // q = LN1(Y1)
        for (int c = 0; c < 2; ++c) {
            gemm_residf<<<gemm_half, 256, 0, stream>>>(
                actB + c * HALF, wtout + (size_t)i * WSZ, bout + i * CDIM,
                q + c * HALF, actAf);
            ln_f<<<lnf_half, 256, 0, stream>>>(
                actAf, ln1g + i * CDIM, ln1b + i * CDIM, q + c * HALF);
        }
        // h = relu(q @ W1) -> actA (Y1 dead)
        gemm_bf16<<<gemm_grid, 256, 0, stream>>>(q, wt1 + (size_t)i * WSZ, nullptr, actA, 1);
        // Y2 = h @ W2 + q  (fp32 chunks via actB; sampled dead); q = LN2(Y2)
        for (int c = 0; c < 2; ++c) {
            gemm_residf<<<gemm_half, 256, 0, stream>>>(
                actA + c * HALF, wt2 + (size_t)i * WSZ, nullptr,
                q + c * HALF, actBf);
            ln_f<<<lnf_half, 256, 0, stream>>>(
                actBf, ln2g + i * CDIM, ln2b + i * CDIM, q + c * HALF);
        }
        // x_{i+1} = q + qpos -> actB (Y2 dead; skip on last layer)
        if (i < LNUM - 1)
            add_bf_kernel<<<addb, 256, 0, stream>>>(q, qpos_bf, actB);
    }

    // scatter back to dense (B, C, H, W) — overwrites all of d_out
    scatter_kernel<<<dim3(NDIM / 32, CDIM / 32, BDIM), blk328, 0, stream>>>(
        q, order, nvalid, (float*)d_out);
}

// Round 6
// 1811.367 us; speedup vs baseline: 1.0353x; 1.0214x over previous
//
#include <hip/hip_runtime.h>
#include <cstdint>
#include <cstddef>

// Problem constants
#define BDIM 2
#define CDIM 512
#define HDIM 128
#define WDIM 128
#define NDIM (HDIM * WDIM)        // 16384
#define LNUM 6
#define NHEADS 8
#define HEAD_DIM 64
#define NPTS 4
#define BN_TOT (BDIM * NDIM)      // 32768

typedef unsigned short u16;
typedef __attribute__((ext_vector_type(8))) short bf16x8;   // 8 bf16 = 4 VGPRs
typedef __attribute__((ext_vector_type(4))) float f32x4;    // MFMA accum

__device__ __forceinline__ u16 f2bf(float x) {              // RNE fp32->bf16
    unsigned u = __float_as_uint(x);
    u += 0x7fffu + ((u >> 16) & 1u);
    return (u16)(u >> 16);
}
__device__ __forceinline__ float bf2f(u16 h) {
    return __uint_as_float(((unsigned)h) << 16);
}

__device__ __forceinline__ void load_lds16(const void* g, void* l) {
    // async global->LDS, 16B/lane; LDS dest = wave-uniform base + lane*16
    __builtin_amdgcn_global_load_lds(
        (const __attribute__((address_space(1))) void*)g,
        (__attribute__((address_space(3))) void*)l, 16, 0, 0);
}

// counted vmem waits (literal-only in asm string)
__device__ __forceinline__ void wait_vm16() { asm volatile("s_waitcnt vmcnt(16)" ::: "memory"); }
__device__ __forceinline__ void wait_vm8()  { asm volatile("s_waitcnt vmcnt(8)" ::: "memory"); }
__device__ __forceinline__ void wait_vm4()  { asm volatile("s_waitcnt vmcnt(4)" ::: "memory"); }
__device__ __forceinline__ void wait_vm0()  { asm volatile("s_waitcnt vmcnt(0)" ::: "memory"); }
__device__ __forceinline__ void sbar()  { __builtin_amdgcn_s_barrier(); }
__device__ __forceinline__ void spin()  { __builtin_amdgcn_sched_barrier(0); }

// ---------------------------------------------------------------------------
// voxelization: mask / order / ref / pack_q(bf16)
// ---------------------------------------------------------------------------
__global__ void mask_kernel(const float* __restrict__ lidar, int* __restrict__ mask)
{
    int idx = blockIdx.x * blockDim.x + threadIdx.x;
    if (idx >= BN_TOT) return;
    int b = idx / NDIM;
    int n = idx - b * NDIM;
    const float* p = lidar + (size_t)b * CDIM * NDIM + n;
    int ok = 1;
#pragma unroll 8
    for (int c = 0; c < CDIM; ++c)
        ok &= (p[(size_t)c * NDIM] != 0.0f);
    mask[idx] = ok;
}

__global__ void order_kernel(const int* __restrict__ mask, int* __restrict__ order,
                             int* __restrict__ nvalid)
{
    int b = blockIdx.x;
    const int* m = mask + b * NDIM;
    int* ord = order + b * NDIM;
    __shared__ int part[256];
    __shared__ int totalValid;
    int t = threadIdx.x;
    const int CHUNK = NDIM / 256;
    int base = t * CHUNK;
    int cnt = 0;
    for (int i = 0; i < CHUNK; ++i) cnt += m[base + i];
    part[t] = cnt;
    __syncthreads();
    for (int s = 1; s < 256; s <<= 1) {
        int v = (t >= s) ? part[t - s] : 0;
        __syncthreads();
        part[t] += v;
        __syncthreads();
    }
    if (t == 255) { totalValid = part[255]; nvalid[b] = part[255]; }
    __syncthreads();
    int validBefore = (t == 0) ? 0 : part[t - 1];
    int nv = totalValid;
    for (int i = 0; i < CHUNK; ++i) {
        int n = base + i;
        if (m[n]) { ord[validBefore] = n; validBefore++; }
        else      { int invBefore = n - validBefore; ord[nv + invBefore] = n; }
    }
}

__global__ void ref_kernel(const int* __restrict__ order, const int* __restrict__ nvalid,
                           float* __restrict__ ref)
{
    int idx = blockIdx.x * blockDim.x + threadIdx.x;
    if (idx >= BN_TOT) return;
    int b = idx / NDIM;
    int j = idx - b * NDIM;
    int n = order[idx];
    float flag = (j < nvalid[b]) ? 1.0f : 0.0f;
    int hh = n / WDIM;
    int ww = n - hh * WDIM;
    ref[(size_t)idx * 2 + 0] = ((float)ww / (float)WDIM) * flag;
    ref[(size_t)idx * 2 + 1] = ((float)hh / (float)HDIM) * flag;
}

__global__ void pack_q_kernel(const float* __restrict__ lidar, const int* __restrict__ order,
                              const int* __restrict__ nvalid, u16* __restrict__ q)
{
    __shared__ float tile[32][33];
    __shared__ int ord_s[32];
    int b  = blockIdx.z;
    int j0 = blockIdx.x * 32;
    int c0 = blockIdx.y * 32;
    int tx = threadIdx.x, ty = threadIdx.y;
    if (ty == 0) ord_s[tx] = order[b * NDIM + j0 + tx];
    __syncthreads();
    const float* src = lidar + (size_t)b * CDIM * NDIM;
#pragma unroll
    for (int k = 0; k < 4; ++k) {
        int cl = ty * 4 + k;
        tile[cl][tx] = src[(size_t)(c0 + cl) * NDIM + ord_s[tx]];
    }
    __syncthreads();
    int nv = nvalid[b];
#pragma unroll
    for (int k = 0; k < 4; ++k) {
        int jl = ty * 4 + k;
        int j = j0 + jl;
        float f = (j < nv) ? 1.0f : 0.0f;
        q[((size_t)b * NDIM + j) * CDIM + c0 + tx] = f2bf(tile[tx][jl] * f);
    }
}

// final scatter: out[b,c,order[j]] = q(bf16)[b,j,c] * valid  (fp32 out)
__global__ void scatter_kernel(const u16* __restrict__ q, const int* __restrict__ order,
                               const int* __restrict__ nvalid, float* __restrict__ out)
{
    __shared__ float tile[32][33];
    __shared__ int ord_s[32];
    int b  = blockIdx.z;
    int j0 = blockIdx.x * 32;
    int c0 = blockIdx.y * 32;
    int tx = threadIdx.x, ty = threadIdx.y;
    if (ty == 0) ord_s[tx] = order[b * NDIM + j0 + tx];
    __syncthreads();
    int nv = nvalid[b];
#pragma unroll
    for (int k = 0; k < 4; ++k) {
        int jl = ty * 4 + k;
        int j = j0 + jl;
        float f = (j < nv) ? 1.0f : 0.0f;
        tile[jl][tx] = bf2f(q[((size_t)b * NDIM + j) * CDIM + c0 + tx]) * f;
    }
    __syncthreads();
    float* dst = out + (size_t)b * CDIM * NDIM;
#pragma unroll
    for (int k = 0; k < 4; ++k) {
        int cl = ty * 4 + k;
        dst[(size_t)(c0 + cl) * NDIM + ord_s[tx]] = tile[tx][cl];
    }
}

// ---------------------------------------------------------------------------
// batched weight transpose-convert: src fp32 [z][512][512] -> dst bf16 [z][N][K]
// ---------------------------------------------------------------------------
__global__ void tconv_b_kernel(const float* __restrict__ src0, u16* __restrict__ dst0)
{
    __shared__ float t[32][33];
    int z = blockIdx.z;
    const float* src = src0 + (size_t)z * 512 * 512;
    u16* dst = dst0 + (size_t)z * 512 * 512;
    int k0 = blockIdx.x * 32, n0 = blockIdx.y * 32;
    int tx = threadIdx.x, ty = threadIdx.y;
#pragma unroll
    for (int j = 0; j < 4; ++j) {
        int kl = ty * 4 + j;
        t[kl][tx] = src[(size_t)(k0 + kl) * 512 + n0 + tx];
    }
    __syncthreads();
#pragma unroll
    for (int j = 0; j < 4; ++j) {
        int nl = ty * 4 + j;
        dst[(size_t)(n0 + nl) * 512 + k0 + tx] = f2bf(t[tx][nl]);
    }
}

// batched: Woff [z][512][64] + Waw [z][512][32] -> dst bf16 [z][96][512]
__global__ void tconv_offaw_b_kernel(const float* __restrict__ woff0,
                                     const float* __restrict__ waw0,
                                     u16* __restrict__ dst0)
{
    __shared__ float t[32][33];
    int z = blockIdx.z;
    const float* woff = woff0 + (size_t)z * 512 * 64;
    const float* waw  = waw0 + (size_t)z * 512 * 32;
    u16* dst = dst0 + (size_t)z * 96 * 512;
    int k0 = blockIdx.x * 32, n0 = blockIdx.y * 32;
    int tx = threadIdx.x, ty = threadIdx.y;
#pragma unroll
    for (int j = 0; j < 4; ++j) {
        int kl = ty * 4 + j;
        int n = n0 + tx;
        float v = (n < 64) ? woff[(size_t)(k0 + kl) * 64 + n]
                           : waw[(size_t)(k0 + kl) * 32 + (n - 64)];
        t[kl][tx] = v;
    }
    __syncthreads();
#pragma unroll
    for (int j = 0; j < 4; ++j) {
        int nl = ty * 4 + j;
        dst[(size_t)(n0 + nl) * 512 + k0 + tx] = f2bf(t[tx][nl]);
    }
}

// bev (B,C,N) fp32 -> featT (B,N,C) bf16
__global__ void bev_conv_kernel(const float* __restrict__ bev, u16* __restrict__ dst)
{
    __shared__ float t[32][33];
    int b  = blockIdx.z;
    int n0 = blockIdx.x * 32;
    int c0 = blockIdx.y * 32;
    int tx = threadIdx.x, ty = threadIdx.y;
    const float* src = bev + (size_t)b * CDIM * NDIM;
#pragma unroll
    for (int j = 0; j < 4; ++j) {
        int cl = ty * 4 + j;
        t[cl][tx] = src[(size_t)(c0 + cl) * NDIM + n0 + tx];
    }
    __syncthreads();
#pragma unroll
    for (int j = 0; j < 4; ++j) {
        int nl = ty * 4 + j;
        dst[((size_t)b * NDIM + n0 + nl) * CDIM + c0 + tx] = f2bf(t[tx][nl]);
    }
}

// ---------------------------------------------------------------------------
// PE hidden: h = relu(BN(ref @ pe_W1))  -> bf16
// ---------------------------------------------------------------------------
__global__ void pe_hidden_kernel(const float* __restrict__ ref, const float* __restrict__ W1,
                                 const float* __restrict__ g, const float* __restrict__ bb,
                                 const float* __restrict__ m, const float* __restrict__ v,
                                 u16* __restrict__ out)
{
    int row = blockIdx.x;
    float r0 = ref[(size_t)row * 2 + 0];
    float r1 = ref[(size_t)row * 2 + 1];
    for (int c = threadIdx.x; c < CDIM; c += blockDim.x) {
        float pe = r0 * W1[c] + r1 * W1[CDIM + c];
        pe = (pe - m[c]) * rsqrtf(v[c] + 1e-5f) * g[c] + bb[c];
        out[(size_t)row * CDIM + c] = f2bf(fmaxf(pe, 0.0f));
    }
}

// ---------------------------------------------------------------------------
// x = q(bf16) + qpos(bf16) -> bf16 ; 8 elements/thread
// ---------------------------------------------------------------------------
__global__ void add_bf_kernel(const u16* __restrict__ q, const u16* __restrict__ qpos,
                              u16* __restrict__ x)
{
    size_t i = (size_t)blockIdx.x * blockDim.x + threadIdx.x;  // 8-el group
    uint4 qa = ((const uint4*)q)[i];
    uint4 pv = ((const uint4*)qpos)[i];
    unsigned qw[4] = {qa.x, qa.y, qa.z, qa.w};
    unsigned pw[4] = {pv.x, pv.y, pv.z, pv.w};
    unsigned rw[4];
#pragma unroll
    for (int k = 0; k < 4; ++k) {
        float a0 = bf2f((u16)(qw[k] & 0xffff)), a1 = bf2f((u16)(qw[k] >> 16));
        float p0 = bf2f((u16)(pw[k] & 0xffff)), p1 = bf2f((u16)(pw[k] >> 16));
        rw[k] = (unsigned)f2bf(a0 + p0) | ((unsigned)f2bf(a1 + p1) << 16);
    }
    uint4 r; r.x = rw[0]; r.y = rw[1]; r.z = rw[2]; r.w = rw[3];
    ((uint4*)x)[i] = r;
}

// ---------------------------------------------------------------------------
// MFMA bf16 GEMM. 128x128 tile, BK=32, 4 waves. 1-D grid of 1024 blocks.
// v5: (a) XCD-aware swizzle — each XCD owns a contiguous band of row-tiles so
// the 4 column-tiles sharing an A row-panel hit ONE XCD's L2 (A HBM-fetched
// once; was 2x). (b) 3-buffer LDS, prefetch depth 2: issue tile t+2, then
// vmcnt(8) — two tiles (8 own DMAs) stay in flight, covering the ~500-900cyc
// staging latency that the depth-1 schedule stalled on every K-step.
// Two raw barriers per step (v4 safety argument unchanged).
// ---------------------------------------------------------------------------
__global__ __launch_bounds__(256) void gemm_bf16(
    const u16* __restrict__ A, const u16* __restrict__ Bt,
    const float* __restrict__ bias, u16* __restrict__ outB, int relu)
{
    __shared__ u16 As[3][128 * 32];   // 24 KB
    __shared__ u16 Bs[3][128 * 32];   // 24 KB
    int tid = threadIdx.x;
    int wave = tid >> 6, lane = tid & 63;
    int wr = wave >> 1, wc = wave & 1;
    int quad = lane >> 4, l15 = lane & 15;
    int lid = blockIdx.x;                        // 1024 blocks
    int tsw = (lid & 7) * 128 + (lid >> 3);      // XCD-contiguous tile id
    int bm = (tsw >> 2) * 128, bn = (tsw & 3) * 128;

    f32x4 acc[4][4];
#pragma unroll
    for (int i = 0; i < 4; ++i)
#pragma unroll
        for (int j = 0; j < 4; ++j) { f32x4 z = {0.f, 0.f, 0.f, 0.f}; acc[i][j] = z; }

    int ch0 = wave, ch1 = wave + 4;
    const u16* Ag0 = A  + (size_t)(bm + ch0 * 16 + (lane >> 2)) * 512 + (lane & 3) * 8;
    const u16* Ag1 = A  + (size_t)(bm + ch1 * 16 + (lane >> 2)) * 512 + (lane & 3) * 8;
    const u16* Bg0 = Bt + (size_t)(bn + ch0 * 16 + (lane >> 2)) * 512 + (lane & 3) * 8;
    const u16* Bg1 = Bt + (size_t)(bn + ch1 * 16 + (lane >> 2)) * 512 + (lane & 3) * 8;

    // prologue: stage tiles 0,1 into buffers 0,1
#pragma unroll
    for (int k = 0; k < 2; ++k) {
        load_lds16(Ag0 + k * 32, &As[k][ch0 * 512]);
        load_lds16(Ag1 + k * 32, &As[k][ch1 * 512]);
        load_lds16(Bg0 + k * 32, &Bs[k][ch0 * 512]);
        load_lds16(Bg1 + k * 32, &Bs[k][ch1 * 512]);
    }

    for (int it = 0; it < 16; ++it) {
        sbar();  spin();                    // prev readers of target buffer done
        int cur = it % 3;
        if (it < 14) {
            int nb = (it + 2) % 3;
            int kn = (it + 2) * 32;
            load_lds16(Ag0 + kn, &As[nb][ch0 * 512]);
            load_lds16(Ag1 + kn, &As[nb][ch1 * 512]);
            load_lds16(Bg0 + kn, &Bs[nb][ch0 * 512]);
            load_lds16(Bg1 + kn, &Bs[nb][ch1 * 512]);
            wait_vm8();                     // own tile-it loads landed; 2 in flight
        } else if (it == 14) {
            wait_vm4();
        } else {
            wait_vm0();
        }
        sbar();  spin();                    // everyone's tile-it loads landed
        bf16x8 av[4], bv[4];
#pragma unroll
        for (int mi = 0; mi < 4; ++mi)
            av[mi] = *(const bf16x8*)&As[cur][(wr * 64 + mi * 16 + l15) * 32 + quad * 8];
#pragma unroll
        for (int ni = 0; ni < 4; ++ni)
            bv[ni] = *(const bf16x8*)&Bs[cur][(wc * 64 + ni * 16 + l15) * 32 + quad * 8];
#pragma unroll
        for (int mi = 0; mi < 4; ++mi)
#pragma unroll
            for (int ni = 0; ni < 4; ++ni)
                acc[mi][ni] = __builtin_amdgcn_mfma_f32_16x16x32_bf16(
                    av[mi], bv[ni], acc[mi][ni], 0, 0, 0);
    }

    int rowb = bm + wr * 64;
    int colb = bn + wc * 64;
#pragma unroll
    for (int mi = 0; mi < 4; ++mi) {
#pragma unroll
        for (int ni = 0; ni < 4; ++ni) {
            int col = colb + ni * 16 + l15;
            float bi = bias ? bias[col] : 0.0f;
#pragma unroll
            for (int r = 0; r < 4; ++r) {
                int row = rowb + mi * 16 + quad * 4 + r;
                float val = acc[mi][ni][r] + bi;
                if (relu) val = fmaxf(val, 0.0f);
                outB[(size_t)row * 512 + col] = f2bf(val);
            }
        }
    }
}

// ---------------------------------------------------------------------------
// gemm_residf: same v5 structure; epilogue writes Y = acc + bias + resid in
// fp32 (no rounding before LN). 16K-row chunk, 1-D grid of 512 blocks.
// ---------------------------------------------------------------------------
__global__ __launch_bounds__(256) void gemm_residf(
    const u16* __restrict__ A, const u16* __restrict__ Bt,
    const float* __restrict__ bias, const u16* __restrict__ resid,
    float* __restrict__ outY)
{
    __shared__ u16 As[3][128 * 32];
    __shared__ u16 Bs[3][128 * 32];
    int tid = threadIdx.x;
    int wave = tid >> 6, lane = tid & 63;
    int wr = wave >> 1, wc = wave & 1;
    int quad = lane >> 4, l15 = lane & 15;
    int lid = blockIdx.x;                        // 512 blocks
    int tsw = (lid & 7) * 64 + (lid >> 3);       // XCD-contiguous tile id
    int bm = (tsw >> 2) * 128, bn = (tsw & 3) * 128;

    f32x4 acc[4][4];
#pragma unroll
    for (int i = 0; i < 4; ++i)
#pragma unroll
        for (int j = 0; j < 4; ++j) { f32x4 z = {0.f, 0.f, 0.f, 0.f}; acc[i][j] = z; }

    int ch0 = wave, ch1 = wave + 4;
    const u16* Ag0 = A  + (size_t)(bm + ch0 * 16 + (lane >> 2)) * 512 + (lane & 3) * 8;
    const u16* Ag1 = A  + (size_t)(bm + ch1 * 16 + (lane >> 2)) * 512 + (lane & 3) * 8;
    const u16* Bg0 = Bt + (size_t)(bn + ch0 * 16 + (lane >> 2)) * 512 + (lane & 3) * 8;
    const u16* Bg1 = Bt + (size_t)(bn + ch1 * 16 + (lane >> 2)) * 512 + (lane & 3) * 8;

#pragma unroll
    for (int k = 0; k < 2; ++k) {
        load_lds16(Ag0 + k * 32, &As[k][ch0 * 512]);
        load_lds16(Ag1 + k * 32, &As[k][ch1 * 512]);
        load_lds16(Bg0 + k * 32, &Bs[k][ch0 * 512]);
        load_lds16(Bg1 + k * 32, &Bs[k][ch1 * 512]);
    }

    for (int it = 0; it < 16; ++it) {
        sbar();  spin();
        int cur = it % 3;
        if (it < 14) {
            int nb = (it + 2) % 3;
            int kn = (it + 2) * 32;
            load_lds16(Ag0 + kn, &As[nb][ch0 * 512]);
            load_lds16(Ag1 + kn, &As[nb][ch1 * 512]);
            load_lds16(Bg0 + kn, &Bs[nb][ch0 * 512]);
            load_lds16(Bg1 + kn, &Bs[nb][ch1 * 512]);
            wait_vm8();
        } else if (it == 14) {
            wait_vm4();
        } else {
            wait_vm0();
        }
        sbar();  spin();
        bf16x8 av[4], bv[4];
#pragma unroll
        for (int mi = 0; mi < 4; ++mi)
            av[mi] = *(const bf16x8*)&As[cur][(wr * 64 + mi * 16 + l15) * 32 + quad * 8];
#pragma unroll
        for (int ni = 0; ni < 4; ++ni)
            bv[ni] = *(const bf16x8*)&Bs[cur][(wc * 64 + ni * 16 + l15) * 32 + quad * 8];
#pragma unroll
        for (int mi = 0; mi < 4; ++mi)
#pragma unroll
            for (int ni = 0; ni < 4; ++ni)
                acc[mi][ni] = __builtin_amdgcn_mfma_f32_16x16x32_bf16(
                    av[mi], bv[ni], acc[mi][ni], 0, 0, 0);
    }

    int rowb = bm + wr * 64;
    int colb = bn + wc * 64;
#pragma unroll
    for (int mi = 0; mi < 4; ++mi) {
#pragma unroll
        for (int ni = 0; ni < 4; ++ni) {
            int col = colb + ni * 16 + l15;
            float bi = bias ? bias[col] : 0.0f;
#pragma unroll
            for (int r = 0; r < 4; ++r) {
                int row = rowb + mi * 16 + quad * 4 + r;
                size_t off = (size_t)row * 512 + col;
                outY[off] = acc[mi][ni][r] + bi + bf2f(resid[off]);
            }
        }
    }
}

// ---------------------------------------------------------------------------
// ln_f: per-row LayerNorm over 512 cols of fp32 Y (chunk-local). One wave per
// row. fp32 stats + fp32 normalize, single bf16 rounding at the output.
// ---------------------------------------------------------------------------
__global__ __launch_bounds__(256) void ln_f(
    const float* __restrict__ Y, const float* __restrict__ g,
    const float* __restrict__ bta, u16* __restrict__ outQ)
{
    int row  = blockIdx.x * 4 + (threadIdx.x >> 6);
    int lane = threadIdx.x & 63;
    size_t base = (size_t)row * CDIM + lane * 8;

    float4 y0 = *(const float4*)(Y + base);
    float4 y1 = *(const float4*)(Y + base + 4);
    float v[8] = {y0.x, y0.y, y0.z, y0.w, y1.x, y1.y, y1.z, y1.w};

    float s = 0.f, s2 = 0.f;
#pragma unroll
    for (int j = 0; j < 8; ++j) { s += v[j]; s2 += v[j] * v[j]; }
#pragma unroll
    for (int m = 1; m < 64; m <<= 1) {
        s  += __shfl_xor(s, m, 64);
        s2 += __shfl_xor(s2, m, 64);
    }
    float mu = s * (1.0f / 512.0f);
    float var = s2 * (1.0f / 512.0f) - mu * mu;
    float iv = rsqrtf(var + 1e-5f);

    int c0 = lane * 8;
    float4 g0 = *(const float4*)(g + c0);
    float4 g1 = *(const float4*)(g + c0 + 4);
    float4 b0 = *(const float4*)(bta + c0);
    float4 b1 = *(const float4*)(bta + c0 + 4);
    float gl[8] = {g0.x, g0.y, g0.z, g0.w, g1.x, g1.y, g1.z, g1.w};
    float bl[8] = {b0.x, b0.y, b0.z, b0.w, b1.x, b1.y, b1.z, b1.w};

    unsigned qw[4];
#pragma unroll
    for (int k = 0; k < 4; ++k) {
        float a = (v[2 * k]     - mu) * iv * gl[2 * k]     + bl[2 * k];
        float b = (v[2 * k + 1] - mu) * iv * gl[2 * k + 1] + bl[2 * k + 1];
        qw[k] = (unsigned)f2bf(a) | ((unsigned)f2bf(b) << 16);
    }
    uint4 qo; qo.x = qw[0]; qo.y = qw[1]; qo.z = qw[2]; qo.w = qw[3];
    *(uint4*)(outQ + base) = qo;
}

// ---------------------------------------------------------------------------
// fused off+aw GEMM: A @ OffAwT[96][512] -> offb/awb. v5: 3-buffer depth-2
// (wave-local staging, single barrier per step as before; vmcnt(16) steady).
// ---------------------------------------------------------------------------
__global__ __launch_bounds__(256) void gemm_offaw(
    const u16* __restrict__ A, const u16* __restrict__ Bt,
    const float* __restrict__ boff, const float* __restrict__ baw,
    u16* __restrict__ offb, u16* __restrict__ awb)
{
    __shared__ u16 As[3][128 * 32];
    __shared__ u16 Bs[3][128 * 32];
    int tid = threadIdx.x;
    int wave = tid >> 6, lane = tid & 63;
    int wr = wave >> 1, wc = wave & 1;
    int quad = lane >> 4, l15 = lane & 15;
    int bm = blockIdx.y * 128;

    f32x4 acc[4][4];
#pragma unroll
    for (int i = 0; i < 4; ++i)
#pragma unroll
        for (int j = 0; j < 4; ++j) { f32x4 z = {0.f, 0.f, 0.f, 0.f}; acc[i][j] = z; }

    // wave-local staging; B rows clamped at 95 (cols >=96 are discarded)
    const u16* Ag[4];
    const u16* Bg[4];
#pragma unroll
    for (int s = 0; s < 4; ++s) {
        Ag[s] = A + (size_t)(bm + wr * 64 + s * 16 + (lane >> 2)) * 512 + (lane & 3) * 8;
        int br = wc * 64 + s * 16 + (lane >> 2);
        if (br > 95) br = 95;
        Bg[s] = Bt + (size_t)br * 512 + (lane & 3) * 8;
    }

    // prologue: tiles 0,1 into buffers 0,1
#pragma unroll
    for (int k = 0; k < 2; ++k)
#pragma unroll
        for (int s = 0; s < 4; ++s) {
            load_lds16(Ag[s] + k * 32, &As[k][(wr * 4 + s) * 512]);
            load_lds16(Bg[s] + k * 32, &Bs[k][(wc * 4 + s) * 512]);
        }

    for (int it = 0; it < 16; ++it) {
        sbar();
        int cur = it % 3;
        if (it < 14) {
            int nb = (it + 2) % 3;
            int kn = (it + 2) * 32;
#pragma unroll
            for (int s = 0; s < 4; ++s) {
                load_lds16(Ag[s] + kn, &As[nb][(wr * 4 + s) * 512]);
                load_lds16(Bg[s] + kn, &Bs[nb][(wc * 4 + s) * 512]);
            }
            wait_vm16();
        } else if (it == 14) {
            wait_vm8();
        } else {
            wait_vm0();
        }
        bf16x8 av[4], bv[4];
#pragma unroll
        for (int mi = 0; mi < 4; ++mi)
            av[mi] = *(const bf16x8*)&As[cur][(wr * 64 + mi * 16 + l15) * 32 + quad * 8];
#pragma unroll
        for (int ni = 0; ni < 4; ++ni)
            bv[ni] = *(const bf16x8*)&Bs[cur][(wc * 64 + ni * 16 + l15) * 32 + quad * 8];
#pragma unroll
        for (int mi = 0; mi < 4; ++mi)
#pragma unroll
            for (int ni = 0; ni < 4; ++ni)
                acc[mi][ni] = __builtin_amdgcn_mfma_f32_16x16x32_bf16(
                    av[mi], bv[ni], acc[mi][ni], 0, 0, 0);
    }

    int rowb = bm + wr * 64;
#pragma unroll
    for (int mi = 0; mi < 4; ++mi) {
#pragma unroll
        for (int ni = 0; ni < 4; ++ni) {
            int col = wc * 64 + ni * 16 + l15;
            if (col < 96) {
                float bi = (col < 64) ? boff[col] : baw[col - 64];
#pragma unroll
                for (int r = 0; r < 4; ++r) {
                    int row = rowb + mi * 16 + quad * 4 + r;
                    float val = acc[mi][ni][r] + bi;
                    if (col < 64) offb[(size_t)row * 64 + col] = f2bf(val);
                    else          awb[(size_t)row * 32 + (col - 64)] = f2bf(val);
                }
            }
        }
    }
}

// ---------------------------------------------------------------------------
// deformable sampling: one wave per (b,j); lane = (head, 8 channels)
// ---------------------------------------------------------------------------
__global__ __launch_bounds__(256) void sample_kernel(
    const float* __restrict__ ref, const u16* __restrict__ off,
    const u16* __restrict__ aw, const u16* __restrict__ v,
    u16* __restrict__ out)
{
    int bj = blockIdx.x * 4 + (threadIdx.x >> 6);   // b*N + j
    int lane = threadIdx.x & 63;
    int h  = lane >> 3;
    int d8 = (lane & 7) * 8;
    int b  = bj >> 14;

    float rx = ref[(size_t)bj * 2 + 0];
    float ry = ref[(size_t)bj * 2 + 1];
    uint4 offv = *(const uint4*)(off + (size_t)bj * 64 + h * 8);
    uint2 awv  = *(const uint2*)(aw + (size_t)bj * 32 + h * 4);

    float l0 = bf2f((u16)(awv.x & 0xffff)), l1 = bf2f((u16)(awv.x >> 16));
    float l2 = bf2f((u16)(awv.y & 0xffff)), l3 = bf2f((u16)(awv.y >> 16));
    float mx = fmaxf(fmaxf(l0, l1), fmaxf(l2, l3));
    float e[4];
    e[0] = expf(l0 - mx); e[1] = expf(l1 - mx);
    e[2] = expf(l2 - mx); e[3] = expf(l3 - mx);
    float inv_es = 1.0f / (e[0] + e[1] + e[2] + e[3]);

    const u16* vb = v + (size_t)b * NDIM * CDIM + h * HEAD_DIM + d8;
    float acc[8] = {0.f, 0.f, 0.f, 0.f, 0.f, 0.f, 0.f, 0.f};
    unsigned ow[4] = {offv.x, offv.y, offv.z, offv.w};

#pragma unroll
    for (int p = 0; p < NPTS; ++p) {
        float ox = bf2f((u16)(ow[p] & 0xffff));
        float oy = bf2f((u16)(ow[p] >> 16));
        float X = rx * (float)WDIM + ox - 0.5f;
        float Y = ry * (float)HDIM + oy - 0.5f;
        float x0f = floorf(X), y0f = floorf(Y);
        float wx = X - x0f, wy = Y - y0f;
        int x0 = (int)x0f, y0 = (int)y0f;
        float ep = e[p];
#pragma unroll
        for (int cy = 0; cy < 2; ++cy) {
            int yy = y0 + cy;
            float wyc = cy ? wy : (1.0f - wy);
            int yin = (yy >= 0) & (yy < HDIM);
            int yc = min(max(yy, 0), HDIM - 1);
#pragma unroll
            for (int cx = 0; cx < 2; ++cx) {
                int xx = x0 + cx;
                float wxc = cx ? wx : (1.0f - wx);
                int xin = (xx >= 0) & (xx < WDIM);
                int xc = min(max(xx, 0), WDIM - 1);
                float wgt = ep * wyc * wxc * (float)(yin & xin);
                uint4 vv = *(const uint4*)(vb + (size_t)(yc * WDIM + xc) * CDIM);
                acc[0] += wgt * bf2f((u16)(vv.x & 0xffff));
                acc[1] += wgt * bf2f((u16)(vv.x >> 16));
                acc[2] += wgt * bf2f((u16)(vv.y & 0xffff));
                acc[3] += wgt * bf2f((u16)(vv.y >> 16));
                acc[4] += wgt * bf2f((u16)(vv.z & 0xffff));
                acc[5] += wgt * bf2f((u16)(vv.z >> 16));
                acc[6] += wgt * bf2f((u16)(vv.w & 0xffff));
                acc[7] += wgt * bf2f((u16)(vv.w >> 16));
            }
        }
    }
    uint4 r;
    r.x = (unsigned)f2bf(acc[0] * inv_es) | ((unsigned)f2bf(acc[1] * inv_es) << 16);
    r.y = (unsigned)f2bf(acc[2] * inv_es) | ((unsigned)f2bf(acc[3] * inv_es) << 16);
    r.z = (unsigned)f2bf(acc[4] * inv_es) | ((unsigned)f2bf(acc[5] * inv_es) << 16);
    r.w = (unsigned)f2bf(acc[6] * inv_es) | ((unsigned)f2bf(acc[7] * inv_es) << 16);
    *(uint4*)(out + (size_t)bj * CDIM + h * HEAD_DIM + d8) = r;
}

// ---------------------------------------------------------------------------
// launcher
// ---------------------------------------------------------------------------
extern "C" void kernel_launch(void* const* d_in, const int* in_sizes, int n_in,
                              void* d_out, int out_size, void* d_ws, size_t ws_size,
                              hipStream_t stream)
{
    const float* bev   = (const float*)d_in[0];
    const float* lidar = (const float*)d_in[1];
    const float* Wv    = (const float*)d_in[2];
    const float* bv    = (const float*)d_in[3];
    const float* Woff  = (const float*)d_in[4];
    const float* boff  = (const float*)d_in[5];
    const float* Waw   = (const float*)d_in[6];
    const float* baw   = (const float*)d_in[7];
    const float* Wout  = (const float*)d_in[8];
    const float* bout  = (const float*)d_in[9];
    const float* ln1g  = (const float*)d_in[10];
    const float* ln1b  = (const float*)d_in[11];
    const float* W1    = (const float*)d_in[12];
    const float* W2    = (const float*)d_in[13];
    const float* ln2g  = (const float*)d_in[14];
    const float* ln2b  = (const float*)d_in[15];
    const float* peW1  = (const float*)d_in[16];
    const float* peg   = (const float*)d_in[17];
    const float* peb   = (const float*)d_in[18];
    const float* pem   = (const float*)d_in[19];
    const float* pev   = (const float*)d_in[20];
    const float* pe_W2 = (const float*)d_in[21];

    const size_t NC   = (size_t)BN_TOT * CDIM;   // 16,777,216 elements
    const size_t HALF = NC / 2;                  // 16K rows worth
    const size_t WSZ  = 512 * 512;               // one square weight

    char* base = (char*)d_ws;
    u16* q      = (u16*)base;                           // NC bf16 (residual stream)
    u16* actA   = (u16*)(base + NC * 2);                // NC bf16 (v / h; fp32 Y1 chunk)
    u16* actB   = (u16*)(base + NC * 4);                // NC bf16 (x / sampled; fp32 Y2 chunk)
    float* actAf = (float*)actA;                        // 16K-row fp32 chunk view (32 MB)
    float* actBf = (float*)actB;                        // 16K-row fp32 chunk view (32 MB)
    u16* wt     = (u16*)(base + NC * 6);                // 25 x 512x512 bf16
    u16* wtv    = wt;                                   // [6]
    u16* wtout  = wt + 6 * WSZ;                         // [6]
    u16* wt1    = wt + 12 * WSZ;                        // [6]
    u16* wt2    = wt + 18 * WSZ;                        // [6]
    u16* wtpe   = wt + 24 * WSZ;                        // [1]
    u16* offawt = wt + 25 * WSZ;                        // 6 x 96x512 bf16
    u16* offb   = offawt + 6 * 96 * 512;                // BN x 64 bf16
    u16* awb    = offb + (size_t)BN_TOT * 64;           // BN x 32 bf16
    float* refb = (float*)(awb + (size_t)BN_TOT * 32);  // BN x 2 fp32
    int* mask   = (int*)(refb + (size_t)BN_TOT * 2);
    int* order  = mask + BN_TOT;
    int* nvalid = order + BN_TOT;

    // d_out doubles as scratch until final scatter:
    u16* qpos_bf = (u16*)d_out;                         // NC bf16 (first half)
    u16* featT   = (u16*)d_out + NC;                    // NC bf16 (second half)

    dim3 blk328(32, 8);
    dim3 offaw_grid(1, 256);
    int  lnf_half = (BN_TOT / 2) / 4;   // 4096 blocks, 4 rows each
    unsigned addb = (unsigned)(NC / 8 / 256);

    // voxelize
    mask_kernel<<<BN_TOT / 256, 256, 0, stream>>>(lidar, mask);
    order_kernel<<<BDIM, 256, 0, stream>>>(mask, order, nvalid);
    ref_kernel<<<BN_TOT / 256, 256, 0, stream>>>(order, nvalid, refb);
    pack_q_kernel<<<dim3(NDIM / 32, CDIM / 32, BDIM), blk328, 0, stream>>>(lidar, order, nvalid, q);
    bev_conv_kernel<<<dim3(NDIM / 32, CDIM / 32, BDIM), blk328, 0, stream>>>(bev, featT);

    // hoisted weight conversions (all layers at once)
    tconv_b_kernel<<<dim3(16, 16, 6), blk328, 0, stream>>>(Wv,   wtv);
    tconv_b_kernel<<<dim3(16, 16, 6), blk328, 0, stream>>>(Wout, wtout);
    tconv_b_kernel<<<dim3(16, 16, 6), blk328, 0, stream>>>(W1,   wt1);
    tconv_b_kernel<<<dim3(16, 16, 6), blk328, 0, stream>>>(W2,   wt2);
    tconv_b_kernel<<<dim3(16, 16, 1), blk328, 0, stream>>>(pe_W2, wtpe);
    tconv_offaw_b_kernel<<<dim3(16, 3, 6), blk328, 0, stream>>>(Woff, Waw, offawt);

    // positional embedding: qpos_bf = relu(BN(ref@peW1)) @ peW2
    pe_hidden_kernel<<<BN_TOT, 128, 0, stream>>>(refb, peW1, peg, peb, pem, pev, actA);
    gemm_bf16<<<1024, 256, 0, stream>>>(actA, wtpe, nullptr, qpos_bf, 0);

    // x0 = q0 + qpos -> actB
    add_bf_kernel<<<addb, 256, 0, stream>>>(q, qpos_bf, actB);

    for (int i = 0; i < LNUM; ++i) {
        // off/aw = x @ [Woff|Waw] + bias   (x lives in actB)
        gemm_offaw<<<offaw_grid, 256, 0, stream>>>(actB, offawt + (size_t)i * 96 * 512,
                                                   boff + i * 64, baw + i * 32, offb, awb);
        // v = featT @ Wv + bv -> actA
        gemm_bf16<<<1024, 256, 0, stream>>>(featT, wtv + (size_t)i * WSZ,
                                            bv + i * CDIM, actA, 0);
        // sampled -> actB (x dead after offaw)
        sample_kernel<<<BN_TOT / 4, 256, 0, stream>>>(refb, offb, awb, actA, actB);
        // Y1 = sampled @ Wout + bout + q  (fp32, 16K-row chunks via actA; v dead)
        // q = LN1(Y1)
        for (int c = 0; c < 2; ++c) {
            gemm_residf<<<512, 256, 0, stream>>>(
                actB + c * HALF, wtout + (size_t)i * WSZ, bout + i * CDIM,
                q + c * HALF, actAf);
            ln_f<<<lnf_half, 256, 0, stream>>>(
                actAf, ln1g + i * CDIM, ln1b + i * CDIM, q + c * HALF);
        }
        // h = relu(q @ W1) -> actA (Y1 dead)
        gemm_bf16<<<1024, 256, 0, stream>>>(q, wt1 + (size_t)i * WSZ, nullptr, actA, 1);
        // Y2 = h @ W2 + q  (fp32 chunks via actB; sampled dead); q = LN2(Y2)
        for (int c = 0; c < 2; ++c) {
            gemm_residf<<<512, 256, 0, stream>>>(
                actA + c * HALF, wt2 + (size_t)i * WSZ, nullptr,
                q + c * HALF, actBf);
            ln_f<<<lnf_half, 256, 0, stream>>>(
                actBf, ln2g + i * CDIM, ln2b + i * CDIM, q + c * HALF);
        }
        // x_{i+1} = q + qpos -> actB (Y2 dead; skip on last layer)
        if (i < LNUM - 1)
            add_bf_kernel<<<addb, 256, 0, stream>>>(q, qpos_bf, actB);
    }

    // scatter back to dense (B, C, H, W) — overwrites all of d_out
    scatter_kernel<<<dim3(NDIM / 32, CDIM / 32, BDIM), blk328, 0, stream>>>(
        q, order, nvalid, (float*)d_out);
}

// Round 7
// 1802.558 us; speedup vs baseline: 1.0403x; 1.0049x over previous
//
#include <hip/hip_runtime.h>
#include <cstdint>
#include <cstddef>

// Problem constants
#define BDIM 2
#define CDIM 512
#define HDIM 128
#define WDIM 128
#define NDIM (HDIM * WDIM)        // 16384
#define LNUM 6
#define NHEADS 8
#define HEAD_DIM 64
#define NPTS 4
#define BN_TOT (BDIM * NDIM)      // 32768

typedef unsigned short u16;
typedef __attribute__((ext_vector_type(8))) short bf16x8;   // 8 bf16 = 4 VGPRs
typedef __attribute__((ext_vector_type(4))) float f32x4;    // MFMA accum

__device__ __forceinline__ u16 f2bf(float x) {              // RNE fp32->bf16
    unsigned u = __float_as_uint(x);
    u += 0x7fffu + ((u >> 16) & 1u);
    return (u16)(u >> 16);
}
__device__ __forceinline__ float bf2f(u16 h) {
    return __uint_as_float(((unsigned)h) << 16);
}

__device__ __forceinline__ void load_lds16(const void* g, void* l) {
    // async global->LDS, 16B/lane; LDS dest = wave-uniform base + lane*16
    __builtin_amdgcn_global_load_lds(
        (const __attribute__((address_space(1))) void*)g,
        (__attribute__((address_space(3))) void*)l, 16, 0, 0);
}

// counted vmem waits (literal-only in asm string)
__device__ __forceinline__ void wait_vm16() { asm volatile("s_waitcnt vmcnt(16)" ::: "memory"); }
__device__ __forceinline__ void wait_vm12() { asm volatile("s_waitcnt vmcnt(12)" ::: "memory"); }
__device__ __forceinline__ void wait_vm8()  { asm volatile("s_waitcnt vmcnt(8)" ::: "memory"); }
__device__ __forceinline__ void wait_vm4()  { asm volatile("s_waitcnt vmcnt(4)" ::: "memory"); }
__device__ __forceinline__ void wait_vm0()  { asm volatile("s_waitcnt vmcnt(0)" ::: "memory"); }
__device__ __forceinline__ void sbar()  { __builtin_amdgcn_s_barrier(); }
__device__ __forceinline__ void spin()  { __builtin_amdgcn_sched_barrier(0); }

// ---------------------------------------------------------------------------
// voxelization: mask / order / ref / pack_q(bf16)
// ---------------------------------------------------------------------------
__global__ void mask_kernel(const float* __restrict__ lidar, int* __restrict__ mask)
{
    int idx = blockIdx.x * blockDim.x + threadIdx.x;
    if (idx >= BN_TOT) return;
    int b = idx / NDIM;
    int n = idx - b * NDIM;
    const float* p = lidar + (size_t)b * CDIM * NDIM + n;
    int ok = 1;
#pragma unroll 8
    for (int c = 0; c < CDIM; ++c)
        ok &= (p[(size_t)c * NDIM] != 0.0f);
    mask[idx] = ok;
}

__global__ void order_kernel(const int* __restrict__ mask, int* __restrict__ order,
                             int* __restrict__ nvalid)
{
    int b = blockIdx.x;
    const int* m = mask + b * NDIM;
    int* ord = order + b * NDIM;
    __shared__ int part[256];
    __shared__ int totalValid;
    int t = threadIdx.x;
    const int CHUNK = NDIM / 256;
    int base = t * CHUNK;
    int cnt = 0;
    for (int i = 0; i < CHUNK; ++i) cnt += m[base + i];
    part[t] = cnt;
    __syncthreads();
    for (int s = 1; s < 256; s <<= 1) {
        int v = (t >= s) ? part[t - s] : 0;
        __syncthreads();
        part[t] += v;
        __syncthreads();
    }
    if (t == 255) { totalValid = part[255]; nvalid[b] = part[255]; }
    __syncthreads();
    int validBefore = (t == 0) ? 0 : part[t - 1];
    int nv = totalValid;
    for (int i = 0; i < CHUNK; ++i) {
        int n = base + i;
        if (m[n]) { ord[validBefore] = n; validBefore++; }
        else      { int invBefore = n - validBefore; ord[nv + invBefore] = n; }
    }
}

__global__ void ref_kernel(const int* __restrict__ order, const int* __restrict__ nvalid,
                           float* __restrict__ ref)
{
    int idx = blockIdx.x * blockDim.x + threadIdx.x;
    if (idx >= BN_TOT) return;
    int b = idx / NDIM;
    int j = idx - b * NDIM;
    int n = order[idx];
    float flag = (j < nvalid[b]) ? 1.0f : 0.0f;
    int hh = n / WDIM;
    int ww = n - hh * WDIM;
    ref[(size_t)idx * 2 + 0] = ((float)ww / (float)WDIM) * flag;
    ref[(size_t)idx * 2 + 1] = ((float)hh / (float)HDIM) * flag;
}

__global__ void pack_q_kernel(const float* __restrict__ lidar, const int* __restrict__ order,
                              const int* __restrict__ nvalid, u16* __restrict__ q)
{
    __shared__ float tile[32][33];
    __shared__ int ord_s[32];
    int b  = blockIdx.z;
    int j0 = blockIdx.x * 32;
    int c0 = blockIdx.y * 32;
    int tx = threadIdx.x, ty = threadIdx.y;
    if (ty == 0) ord_s[tx] = order[b * NDIM + j0 + tx];
    __syncthreads();
    const float* src = lidar + (size_t)b * CDIM * NDIM;
#pragma unroll
    for (int k = 0; k < 4; ++k) {
        int cl = ty * 4 + k;
        tile[cl][tx] = src[(size_t)(c0 + cl) * NDIM + ord_s[tx]];
    }
    __syncthreads();
    int nv = nvalid[b];
#pragma unroll
    for (int k = 0; k < 4; ++k) {
        int jl = ty * 4 + k;
        int j = j0 + jl;
        float f = (j < nv) ? 1.0f : 0.0f;
        q[((size_t)b * NDIM + j) * CDIM + c0 + tx] = f2bf(tile[tx][jl] * f);
    }
}

// final scatter: out[b,c,order[j]] = q(bf16)[b,j,c] * valid  (fp32 out)
__global__ void scatter_kernel(const u16* __restrict__ q, const int* __restrict__ order,
                               const int* __restrict__ nvalid, float* __restrict__ out)
{
    __shared__ float tile[32][33];
    __shared__ int ord_s[32];
    int b  = blockIdx.z;
    int j0 = blockIdx.x * 32;
    int c0 = blockIdx.y * 32;
    int tx = threadIdx.x, ty = threadIdx.y;
    if (ty == 0) ord_s[tx] = order[b * NDIM + j0 + tx];
    __syncthreads();
    int nv = nvalid[b];
#pragma unroll
    for (int k = 0; k < 4; ++k) {
        int jl = ty * 4 + k;
        int j = j0 + jl;
        float f = (j < nv) ? 1.0f : 0.0f;
        tile[jl][tx] = bf2f(q[((size_t)b * NDIM + j) * CDIM + c0 + tx]) * f;
    }
    __syncthreads();
    float* dst = out + (size_t)b * CDIM * NDIM;
#pragma unroll
    for (int k = 0; k < 4; ++k) {
        int cl = ty * 4 + k;
        dst[(size_t)(c0 + cl) * NDIM + ord_s[tx]] = tile[tx][cl];
    }
}

// ---------------------------------------------------------------------------
// batched weight transpose-convert: src fp32 [z][512][512] -> dst bf16 [z][N][K]
// ---------------------------------------------------------------------------
__global__ void tconv_b_kernel(const float* __restrict__ src0, u16* __restrict__ dst0)
{
    __shared__ float t[32][33];
    int z = blockIdx.z;
    const float* src = src0 + (size_t)z * 512 * 512;
    u16* dst = dst0 + (size_t)z * 512 * 512;
    int k0 = blockIdx.x * 32, n0 = blockIdx.y * 32;
    int tx = threadIdx.x, ty = threadIdx.y;
#pragma unroll
    for (int j = 0; j < 4; ++j) {
        int kl = ty * 4 + j;
        t[kl][tx] = src[(size_t)(k0 + kl) * 512 + n0 + tx];
    }
    __syncthreads();
#pragma unroll
    for (int j = 0; j < 4; ++j) {
        int nl = ty * 4 + j;
        dst[(size_t)(n0 + nl) * 512 + k0 + tx] = f2bf(t[tx][nl]);
    }
}

// batched: Woff [z][512][64] + Waw [z][512][32] -> dst bf16 [z][96][512]
__global__ void tconv_offaw_b_kernel(const float* __restrict__ woff0,
                                     const float* __restrict__ waw0,
                                     u16* __restrict__ dst0)
{
    __shared__ float t[32][33];
    int z = blockIdx.z;
    const float* woff = woff0 + (size_t)z * 512 * 64;
    const float* waw  = waw0 + (size_t)z * 512 * 32;
    u16* dst = dst0 + (size_t)z * 96 * 512;
    int k0 = blockIdx.x * 32, n0 = blockIdx.y * 32;
    int tx = threadIdx.x, ty = threadIdx.y;
#pragma unroll
    for (int j = 0; j < 4; ++j) {
        int kl = ty * 4 + j;
        int n = n0 + tx;
        float v = (n < 64) ? woff[(size_t)(k0 + kl) * 64 + n]
                           : waw[(size_t)(k0 + kl) * 32 + (n - 64)];
        t[kl][tx] = v;
    }
    __syncthreads();
#pragma unroll
    for (int j = 0; j < 4; ++j) {
        int nl = ty * 4 + j;
        dst[(size_t)(n0 + nl) * 512 + k0 + tx] = f2bf(t[tx][nl]);
    }
}

// bev (B,C,N) fp32 -> featT (B,N,C) bf16
__global__ void bev_conv_kernel(const float* __restrict__ bev, u16* __restrict__ dst)
{
    __shared__ float t[32][33];
    int b  = blockIdx.z;
    int n0 = blockIdx.x * 32;
    int c0 = blockIdx.y * 32;
    int tx = threadIdx.x, ty = threadIdx.y;
    const float* src = bev + (size_t)b * CDIM * NDIM;
#pragma unroll
    for (int j = 0; j < 4; ++j) {
        int cl = ty * 4 + j;
        t[cl][tx] = src[(size_t)(c0 + cl) * NDIM + n0 + tx];
    }
    __syncthreads();
#pragma unroll
    for (int j = 0; j < 4; ++j) {
        int nl = ty * 4 + j;
        dst[((size_t)b * NDIM + n0 + nl) * CDIM + c0 + tx] = f2bf(t[tx][nl]);
    }
}

// ---------------------------------------------------------------------------
// PE hidden: h = relu(BN(ref @ pe_W1))  -> bf16
// ---------------------------------------------------------------------------
__global__ void pe_hidden_kernel(const float* __restrict__ ref, const float* __restrict__ W1,
                                 const float* __restrict__ g, const float* __restrict__ bb,
                                 const float* __restrict__ m, const float* __restrict__ v,
                                 u16* __restrict__ out)
{
    int row = blockIdx.x;
    float r0 = ref[(size_t)row * 2 + 0];
    float r1 = ref[(size_t)row * 2 + 1];
    for (int c = threadIdx.x; c < CDIM; c += blockDim.x) {
        float pe = r0 * W1[c] + r1 * W1[CDIM + c];
        pe = (pe - m[c]) * rsqrtf(v[c] + 1e-5f) * g[c] + bb[c];
        out[(size_t)row * CDIM + c] = f2bf(fmaxf(pe, 0.0f));
    }
}

// ---------------------------------------------------------------------------
// x = q(bf16) + qpos(bf16) -> bf16 ; 8 elements/thread
// ---------------------------------------------------------------------------
__global__ void add_bf_kernel(const u16* __restrict__ q, const u16* __restrict__ qpos,
                              u16* __restrict__ x)
{
    size_t i = (size_t)blockIdx.x * blockDim.x + threadIdx.x;  // 8-el group
    uint4 qa = ((const uint4*)q)[i];
    uint4 pv = ((const uint4*)qpos)[i];
    unsigned qw[4] = {qa.x, qa.y, qa.z, qa.w};
    unsigned pw[4] = {pv.x, pv.y, pv.z, pv.w};
    unsigned rw[4];
#pragma unroll
    for (int k = 0; k < 4; ++k) {
        float a0 = bf2f((u16)(qw[k] & 0xffff)), a1 = bf2f((u16)(qw[k] >> 16));
        float p0 = bf2f((u16)(pw[k] & 0xffff)), p1 = bf2f((u16)(pw[k] >> 16));
        rw[k] = (unsigned)f2bf(a0 + p0) | ((unsigned)f2bf(a1 + p1) << 16);
    }
    uint4 r; r.x = rw[0]; r.y = rw[1]; r.z = rw[2]; r.w = rw[3];
    ((uint4*)x)[i] = r;
}

// ---------------------------------------------------------------------------
// MFMA bf16 GEMM — v6: 256x256 tile, BK=32, 8 waves (512 thr), grid = 256.
// Rationale: measured law across r0-r6 is dur ~= staged_bytes / ~6 TB/s (all
// configs with >=2 blocks/CU fit within 10%). Staged total = A*(512/BN) +
// 0.5MB*(32768/BM); 256x256 minimizes it at 128 MB (vs 256 MB for 128x128).
// Grid 256 = 1 block/CU, which killed v4 at depth-1 — so this uses 4-buffer
// LDS with prefetch DEPTH 3: issue tile t+3, vmcnt(12) (3 steps x 4 own DMAs
// in flight ~= 1700 cyc latency cover). Two raw barriers per step (v4 safety
// argument: every wave passes its own counted vmcnt before barrier 2, so all
// staging for the tile being read is complete). XCD swizzle: each XCD owns 16
// row-panels x both col-tiles -> its A band = 4 MB = L2-resident.
// Per-wave: wave grid 2M x 4N, output 128x64, acc[8][4] (~210 VGPR).
// ---------------------------------------------------------------------------
__global__ __launch_bounds__(512) void gemm_bf16(
    const u16* __restrict__ A, const u16* __restrict__ Bt,
    const float* __restrict__ bias, u16* __restrict__ outB, int relu)
{
    __shared__ u16 As[4][256 * 32];   // 64 KB
    __shared__ u16 Bs[4][256 * 32];   // 64 KB
    int tid = threadIdx.x;
    int wave = tid >> 6, lane = tid & 63;
    int wr = wave >> 2, wc = wave & 3;           // wave grid 2 (M) x 4 (N)
    int quad = lane >> 4, l15 = lane & 15;
    int lid = blockIdx.x;                        // 256 blocks
    int tsw = (lid & 7) * 32 + (lid >> 3);       // XCD-contiguous tile id
    int bm = (tsw >> 1) * 256, bn = (tsw & 1) * 256;

    f32x4 acc[8][4];
#pragma unroll
    for (int i = 0; i < 8; ++i)
#pragma unroll
        for (int j = 0; j < 4; ++j) { f32x4 z = {0.f, 0.f, 0.f, 0.f}; acc[i][j] = z; }

    // staging ownership: 16 A-chunks + 16 B-chunks of 16 rows x 32 cols (1 KB);
    // wave w owns A-chunks {2w,2w+1} and B-chunks {2w,2w+1} (4 DMAs/step).
    int c0 = wave * 2, c1 = wave * 2 + 1;
    const u16* Ag0 = A  + (size_t)(bm + c0 * 16 + (lane >> 2)) * 512 + (lane & 3) * 8;
    const u16* Ag1 = A  + (size_t)(bm + c1 * 16 + (lane >> 2)) * 512 + (lane & 3) * 8;
    const u16* Bg0 = Bt + (size_t)(bn + c0 * 16 + (lane >> 2)) * 512 + (lane & 3) * 8;
    const u16* Bg1 = Bt + (size_t)(bn + c1 * 16 + (lane >> 2)) * 512 + (lane & 3) * 8;

    // prologue: stage tiles 0,1,2 into buffers 0,1,2
#pragma unroll
    for (int k = 0; k < 3; ++k) {
        load_lds16(Ag0 + k * 32, &As[k][c0 * 512]);
        load_lds16(Ag1 + k * 32, &As[k][c1 * 512]);
        load_lds16(Bg0 + k * 32, &Bs[k][c0 * 512]);
        load_lds16(Bg1 + k * 32, &Bs[k][c1 * 512]);
    }

    for (int it = 0; it < 16; ++it) {
        sbar();  spin();                    // prev readers of target buffer done
        int cur = it & 3;
        if (it < 13) {
            int nb = (it + 3) & 3;
            int kn = (it + 3) * 32;
            load_lds16(Ag0 + kn, &As[nb][c0 * 512]);
            load_lds16(Ag1 + kn, &As[nb][c1 * 512]);
            load_lds16(Bg0 + kn, &Bs[nb][c0 * 512]);
            load_lds16(Bg1 + kn, &Bs[nb][c1 * 512]);
            wait_vm12();                    // own tile-it loads landed; 3 in flight
        } else if (it == 13) {
            wait_vm8();
        } else if (it == 14) {
            wait_vm4();
        } else {
            wait_vm0();
        }
        sbar();  spin();                    // everyone's tile-it loads landed
        bf16x8 av[8], bv[4];
#pragma unroll
        for (int mi = 0; mi < 8; ++mi)
            av[mi] = *(const bf16x8*)&As[cur][(wr * 128 + mi * 16 + l15) * 32 + quad * 8];
#pragma unroll
        for (int ni = 0; ni < 4; ++ni)
            bv[ni] = *(const bf16x8*)&Bs[cur][(wc * 64 + ni * 16 + l15) * 32 + quad * 8];
#pragma unroll
        for (int mi = 0; mi < 8; ++mi)
#pragma unroll
            for (int ni = 0; ni < 4; ++ni)
                acc[mi][ni] = __builtin_amdgcn_mfma_f32_16x16x32_bf16(
                    av[mi], bv[ni], acc[mi][ni], 0, 0, 0);
    }

    int rowb = bm + wr * 128;
    int colb = bn + wc * 64;
#pragma unroll
    for (int mi = 0; mi < 8; ++mi) {
#pragma unroll
        for (int ni = 0; ni < 4; ++ni) {
            int col = colb + ni * 16 + l15;
            float bi = bias ? bias[col] : 0.0f;
#pragma unroll
            for (int r = 0; r < 4; ++r) {
                int row = rowb + mi * 16 + quad * 4 + r;
                float val = acc[mi][ni][r] + bi;
                if (relu) val = fmaxf(val, 0.0f);
                outB[(size_t)row * 512 + col] = f2bf(val);
            }
        }
    }
}

// ---------------------------------------------------------------------------
// gemm_residf: v5 structure kept (128x128, depth-2, XCD swizzle); epilogue
// writes Y = acc + bias + resid in fp32 (no rounding before LN).
// 16K-row chunk, 1-D grid of 512 blocks.
// ---------------------------------------------------------------------------
__global__ __launch_bounds__(256) void gemm_residf(
    const u16* __restrict__ A, const u16* __restrict__ Bt,
    const float* __restrict__ bias, const u16* __restrict__ resid,
    float* __restrict__ outY)
{
    __shared__ u16 As[3][128 * 32];
    __shared__ u16 Bs[3][128 * 32];
    int tid = threadIdx.x;
    int wave = tid >> 6, lane = tid & 63;
    int wr = wave >> 1, wc = wave & 1;
    int quad = lane >> 4, l15 = lane & 15;
    int lid = blockIdx.x;                        // 512 blocks
    int tsw = (lid & 7) * 64 + (lid >> 3);       // XCD-contiguous tile id
    int bm = (tsw >> 2) * 128, bn = (tsw & 3) * 128;

    f32x4 acc[4][4];
#pragma unroll
    for (int i = 0; i < 4; ++i)
#pragma unroll
        for (int j = 0; j < 4; ++j) { f32x4 z = {0.f, 0.f, 0.f, 0.f}; acc[i][j] = z; }

    int ch0 = wave, ch1 = wave + 4;
    const u16* Ag0 = A  + (size_t)(bm + ch0 * 16 + (lane >> 2)) * 512 + (lane & 3) * 8;
    const u16* Ag1 = A  + (size_t)(bm + ch1 * 16 + (lane >> 2)) * 512 + (lane & 3) * 8;
    const u16* Bg0 = Bt + (size_t)(bn + ch0 * 16 + (lane >> 2)) * 512 + (lane & 3) * 8;
    const u16* Bg1 = Bt + (size_t)(bn + ch1 * 16 + (lane >> 2)) * 512 + (lane & 3) * 8;

#pragma unroll
    for (int k = 0; k < 2; ++k) {
        load_lds16(Ag0 + k * 32, &As[k][ch0 * 512]);
        load_lds16(Ag1 + k * 32, &As[k][ch1 * 512]);
        load_lds16(Bg0 + k * 32, &Bs[k][ch0 * 512]);
        load_lds16(Bg1 + k * 32, &Bs[k][ch1 * 512]);
    }

    for (int it = 0; it < 16; ++it) {
        sbar();  spin();
        int cur = it % 3;
        if (it < 14) {
            int nb = (it + 2) % 3;
            int kn = (it + 2) * 32;
            load_lds16(Ag0 + kn, &As[nb][ch0 * 512]);
            load_lds16(Ag1 + kn, &As[nb][ch1 * 512]);
            load_lds16(Bg0 + kn, &Bs[nb][ch0 * 512]);
            load_lds16(Bg1 + kn, &Bs[nb][ch1 * 512]);
            wait_vm8();
        } else if (it == 14) {
            wait_vm4();
        } else {
            wait_vm0();
        }
        sbar();  spin();
        bf16x8 av[4], bv[4];
#pragma unroll
        for (int mi = 0; mi < 4; ++mi)
            av[mi] = *(const bf16x8*)&As[cur][(wr * 64 + mi * 16 + l15) * 32 + quad * 8];
#pragma unroll
        for (int ni = 0; ni < 4; ++ni)
            bv[ni] = *(const bf16x8*)&Bs[cur][(wc * 64 + ni * 16 + l15) * 32 + quad * 8];
#pragma unroll
        for (int mi = 0; mi < 4; ++mi)
#pragma unroll
            for (int ni = 0; ni < 4; ++ni)
                acc[mi][ni] = __builtin_amdgcn_mfma_f32_16x16x32_bf16(
                    av[mi], bv[ni], acc[mi][ni], 0, 0, 0);
    }

    int rowb = bm + wr * 64;
    int colb = bn + wc * 64;
#pragma unroll
    for (int mi = 0; mi < 4; ++mi) {
#pragma unroll
        for (int ni = 0; ni < 4; ++ni) {
            int col = colb + ni * 16 + l15;
            float bi = bias ? bias[col] : 0.0f;
#pragma unroll
            for (int r = 0; r < 4; ++r) {
                int row = rowb + mi * 16 + quad * 4 + r;
                size_t off = (size_t)row * 512 + col;
                outY[off] = acc[mi][ni][r] + bi + bf2f(resid[off]);
            }
        }
    }
}

// ---------------------------------------------------------------------------
// ln_f: per-row LayerNorm over 512 cols of fp32 Y (chunk-local). One wave per
// row. fp32 stats + fp32 normalize, single bf16 rounding at the output.
// ---------------------------------------------------------------------------
__global__ __launch_bounds__(256) void ln_f(
    const float* __restrict__ Y, const float* __restrict__ g,
    const float* __restrict__ bta, u16* __restrict__ outQ)
{
    int row  = blockIdx.x * 4 + (threadIdx.x >> 6);
    int lane = threadIdx.x & 63;
    size_t base = (size_t)row * CDIM + lane * 8;

    float4 y0 = *(const float4*)(Y + base);
    float4 y1 = *(const float4*)(Y + base + 4);
    float v[8] = {y0.x, y0.y, y0.z, y0.w, y1.x, y1.y, y1.z, y1.w};

    float s = 0.f, s2 = 0.f;
#pragma unroll
    for (int j = 0; j < 8; ++j) { s += v[j]; s2 += v[j] * v[j]; }
#pragma unroll
    for (int m = 1; m < 64; m <<= 1) {
        s  += __shfl_xor(s, m, 64);
        s2 += __shfl_xor(s2, m, 64);
    }
    float mu = s * (1.0f / 512.0f);
    float var = s2 * (1.0f / 512.0f) - mu * mu;
    float iv = rsqrtf(var + 1e-5f);

    int c0 = lane * 8;
    float4 g0 = *(const float4*)(g + c0);
    float4 g1 = *(const float4*)(g + c0 + 4);
    float4 b0 = *(const float4*)(bta + c0);
    float4 b1 = *(const float4*)(bta + c0 + 4);
    float gl[8] = {g0.x, g0.y, g0.z, g0.w, g1.x, g1.y, g1.z, g1.w};
    float bl[8] = {b0.x, b0.y, b0.z, b0.w, b1.x, b1.y, b1.z, b1.w};

    unsigned qw[4];
#pragma unroll
    for (int k = 0; k < 4; ++k) {
        float a = (v[2 * k]     - mu) * iv * gl[2 * k]     + bl[2 * k];
        float b = (v[2 * k + 1] - mu) * iv * gl[2 * k + 1] + bl[2 * k + 1];
        qw[k] = (unsigned)f2bf(a) | ((unsigned)f2bf(b) << 16);
    }
    uint4 qo; qo.x = qw[0]; qo.y = qw[1]; qo.z = qw[2]; qo.w = qw[3];
    *(uint4*)(outQ + base) = qo;
}

// ---------------------------------------------------------------------------
// fused off+aw GEMM: A @ OffAwT[96][512] -> offb/awb. 3-buffer depth-2
// (wave-local staging, single barrier per step; vmcnt(16) steady).
// ---------------------------------------------------------------------------
__global__ __launch_bounds__(256) void gemm_offaw(
    const u16* __restrict__ A, const u16* __restrict__ Bt,
    const float* __restrict__ boff, const float* __restrict__ baw,
    u16* __restrict__ offb, u16* __restrict__ awb)
{
    __shared__ u16 As[3][128 * 32];
    __shared__ u16 Bs[3][128 * 32];
    int tid = threadIdx.x;
    int wave = tid >> 6, lane = tid & 63;
    int wr = wave >> 1, wc = wave & 1;
    int quad = lane >> 4, l15 = lane & 15;
    int bm = blockIdx.y * 128;

    f32x4 acc[4][4];
#pragma unroll
    for (int i = 0; i < 4; ++i)
#pragma unroll
        for (int j = 0; j < 4; ++j) { f32x4 z = {0.f, 0.f, 0.f, 0.f}; acc[i][j] = z; }

    // wave-local staging; B rows clamped at 95 (cols >=96 are discarded)
    const u16* Ag[4];
    const u16* Bg[4];
#pragma unroll
    for (int s = 0; s < 4; ++s) {
        Ag[s] = A + (size_t)(bm + wr * 64 + s * 16 + (lane >> 2)) * 512 + (lane & 3) * 8;
        int br = wc * 64 + s * 16 + (lane >> 2);
        if (br > 95) br = 95;
        Bg[s] = Bt + (size_t)br * 512 + (lane & 3) * 8;
    }

    // prologue: tiles 0,1 into buffers 0,1
#pragma unroll
    for (int k = 0; k < 2; ++k)
#pragma unroll
        for (int s = 0; s < 4; ++s) {
            load_lds16(Ag[s] + k * 32, &As[k][(wr * 4 + s) * 512]);
            load_lds16(Bg[s] + k * 32, &Bs[k][(wc * 4 + s) * 512]);
        }

    for (int it = 0; it < 16; ++it) {
        sbar();
        int cur = it % 3;
        if (it < 14) {
            int nb = (it + 2) % 3;
            int kn = (it + 2) * 32;
#pragma unroll
            for (int s = 0; s < 4; ++s) {
                load_lds16(Ag[s] + kn, &As[nb][(wr * 4 + s) * 512]);
                load_lds16(Bg[s] + kn, &Bs[nb][(wc * 4 + s) * 512]);
            }
            wait_vm16();
        } else if (it == 14) {
            wait_vm8();
        } else {
            wait_vm0();
        }
        bf16x8 av[4], bv[4];
#pragma unroll
        for (int mi = 0; mi < 4; ++mi)
            av[mi] = *(const bf16x8*)&As[cur][(wr * 64 + mi * 16 + l15) * 32 + quad * 8];
#pragma unroll
        for (int ni = 0; ni < 4; ++ni)
            bv[ni] = *(const bf16x8*)&Bs[cur][(wc * 64 + ni * 16 + l15) * 32 + quad * 8];
#pragma unroll
        for (int mi = 0; mi < 4; ++mi)
#pragma unroll
            for (int ni = 0; ni < 4; ++ni)
                acc[mi][ni] = __builtin_amdgcn_mfma_f32_16x16x32_bf16(
                    av[mi], bv[ni], acc[mi][ni], 0, 0, 0);
    }

    int rowb = bm + wr * 64;
#pragma unroll
    for (int mi = 0; mi < 4; ++mi) {
#pragma unroll
        for (int ni = 0; ni < 4; ++ni) {
            int col = wc * 64 + ni * 16 + l15;
            if (col < 96) {
                float bi = (col < 64) ? boff[col] : baw[col - 64];
#pragma unroll
                for (int r = 0; r < 4; ++r) {
                    int row = rowb + mi * 16 + quad * 4 + r;
                    float val = acc[mi][ni][r] + bi;
                    if (col < 64) offb[(size_t)row * 64 + col] = f2bf(val);
                    else          awb[(size_t)row * 32 + (col - 64)] = f2bf(val);
                }
            }
        }
    }
}

// ---------------------------------------------------------------------------
// deformable sampling: one wave per (b,j); lane = (head, 8 channels)
// ---------------------------------------------------------------------------
__global__ __launch_bounds__(256) void sample_kernel(
    const float* __restrict__ ref, const u16* __restrict__ off,
    const u16* __restrict__ aw, const u16* __restrict__ v,
    u16* __restrict__ out)
{
    int bj = blockIdx.x * 4 + (threadIdx.x >> 6);   // b*N + j
    int lane = threadIdx.x & 63;
    int h  = lane >> 3;
    int d8 = (lane & 7) * 8;
    int b  = bj >> 14;

    float rx = ref[(size_t)bj * 2 + 0];
    float ry = ref[(size_t)bj * 2 + 1];
    uint4 offv = *(const uint4*)(off + (size_t)bj * 64 + h * 8);
    uint2 awv  = *(const uint2*)(aw + (size_t)bj * 32 + h * 4);

    float l0 = bf2f((u16)(awv.x & 0xffff)), l1 = bf2f((u16)(awv.x >> 16));
    float l2 = bf2f((u16)(awv.y & 0xffff)), l3 = bf2f((u16)(awv.y >> 16));
    float mx = fmaxf(fmaxf(l0, l1), fmaxf(l2, l3));
    float e[4];
    e[0] = expf(l0 - mx); e[1] = expf(l1 - mx);
    e[2] = expf(l2 - mx); e[3] = expf(l3 - mx);
    float inv_es = 1.0f / (e[0] + e[1] + e[2] + e[3]);

    const u16* vb = v + (size_t)b * NDIM * CDIM + h * HEAD_DIM + d8;
    float acc[8] = {0.f, 0.f, 0.f, 0.f, 0.f, 0.f, 0.f, 0.f};
    unsigned ow[4] = {offv.x, offv.y, offv.z, offv.w};

#pragma unroll
    for (int p = 0; p < NPTS; ++p) {
        float ox = bf2f((u16)(ow[p] & 0xffff));
        float oy = bf2f((u16)(ow[p] >> 16));
        float X = rx * (float)WDIM + ox - 0.5f;
        float Y = ry * (float)HDIM + oy - 0.5f;
        float x0f = floorf(X), y0f = floorf(Y);
        float wx = X - x0f, wy = Y - y0f;
        int x0 = (int)x0f, y0 = (int)y0f;
        float ep = e[p];
#pragma unroll
        for (int cy = 0; cy < 2; ++cy) {
            int yy = y0 + cy;
            float wyc = cy ? wy : (1.0f - wy);
            int yin = (yy >= 0) & (yy < HDIM);
            int yc = min(max(yy, 0), HDIM - 1);
#pragma unroll
            for (int cx = 0; cx < 2; ++cx) {
                int xx = x0 + cx;
                float wxc = cx ? wx : (1.0f - wx);
                int xin = (xx >= 0) & (xx < WDIM);
                int xc = min(max(xx, 0), WDIM - 1);
                float wgt = ep * wyc * wxc * (float)(yin & xin);
                uint4 vv = *(const uint4*)(vb + (size_t)(yc * WDIM + xc) * CDIM);
                acc[0] += wgt * bf2f((u16)(vv.x & 0xffff));
                acc[1] += wgt * bf2f((u16)(vv.x >> 16));
                acc[2] += wgt * bf2f((u16)(vv.y & 0xffff));
                acc[3] += wgt * bf2f((u16)(vv.y >> 16));
                acc[4] += wgt * bf2f((u16)(vv.z & 0xffff));
                acc[5] += wgt * bf2f((u16)(vv.z >> 16));
                acc[6] += wgt * bf2f((u16)(vv.w & 0xffff));
                acc[7] += wgt * bf2f((u16)(vv.w >> 16));
            }
        }
    }
    uint4 r;
    r.x = (unsigned)f2bf(acc[0] * inv_es) | ((unsigned)f2bf(acc[1] * inv_es) << 16);
    r.y = (unsigned)f2bf(acc[2] * inv_es) | ((unsigned)f2bf(acc[3] * inv_es) << 16);
    r.z = (unsigned)f2bf(acc[4] * inv_es) | ((unsigned)f2bf(acc[5] * inv_es) << 16);
    r.w = (unsigned)f2bf(acc[6] * inv_es) | ((unsigned)f2bf(acc[7] * inv_es) << 16);
    *(uint4*)(out + (size_t)bj * CDIM + h * HEAD_DIM + d8) = r;
}

// ---------------------------------------------------------------------------
// launcher
// ---------------------------------------------------------------------------
extern "C" void kernel_launch(void* const* d_in, const int* in_sizes, int n_in,
                              void* d_out, int out_size, void* d_ws, size_t ws_size,
                              hipStream_t stream)
{
    const float* bev   = (const float*)d_in[0];
    const float* lidar = (const float*)d_in[1];
    const float* Wv    = (const float*)d_in[2];
    const float* bv    = (const float*)d_in[3];
    const float* Woff  = (const float*)d_in[4];
    const float* boff  = (const float*)d_in[5];
    const float* Waw   = (const float*)d_in[6];
    const float* baw   = (const float*)d_in[7];
    const float* Wout  = (const float*)d_in[8];
    const float* bout  = (const float*)d_in[9];
    const float* ln1g  = (const float*)d_in[10];
    const float* ln1b  = (const float*)d_in[11];
    const float* W1    = (const float*)d_in[12];
    const float* W2    = (const float*)d_in[13];
    const float* ln2g  = (const float*)d_in[14];
    const float* ln2b  = (const float*)d_in[15];
    const float* peW1  = (const float*)d_in[16];
    const float* peg   = (const float*)d_in[17];
    const float* peb   = (const float*)d_in[18];
    const float* pem   = (const float*)d_in[19];
    const float* pev   = (const float*)d_in[20];
    const float* pe_W2 = (const float*)d_in[21];

    const size_t NC   = (size_t)BN_TOT * CDIM;   // 16,777,216 elements
    const size_t HALF = NC / 2;                  // 16K rows worth
    const size_t WSZ  = 512 * 512;               // one square weight

    char* base = (char*)d_ws;
    u16* q      = (u16*)base;                           // NC bf16 (residual stream)
    u16* actA   = (u16*)(base + NC * 2);                // NC bf16 (v / h; fp32 Y1 chunk)
    u16* actB   = (u16*)(base + NC * 4);                // NC bf16 (x / sampled; fp32 Y2 chunk)
    float* actAf = (float*)actA;                        // 16K-row fp32 chunk view (32 MB)
    float* actBf = (float*)actB;                        // 16K-row fp32 chunk view (32 MB)
    u16* wt     = (u16*)(base + NC * 6);                // 25 x 512x512 bf16
    u16* wtv    = wt;                                   // [6]
    u16* wtout  = wt + 6 * WSZ;                         // [6]
    u16* wt1    = wt + 12 * WSZ;                        // [6]
    u16* wt2    = wt + 18 * WSZ;                        // [6]
    u16* wtpe   = wt + 24 * WSZ;                        // [1]
    u16* offawt = wt + 25 * WSZ;                        // 6 x 96x512 bf16
    u16* offb   = offawt + 6 * 96 * 512;                // BN x 64 bf16
    u16* awb    = offb + (size_t)BN_TOT * 64;           // BN x 32 bf16
    float* refb = (float*)(awb + (size_t)BN_TOT * 32);  // BN x 2 fp32
    int* mask   = (int*)(refb + (size_t)BN_TOT * 2);
    int* order  = mask + BN_TOT;
    int* nvalid = order + BN_TOT;

    // d_out doubles as scratch until final scatter:
    u16* qpos_bf = (u16*)d_out;                         // NC bf16 (first half)
    u16* featT   = (u16*)d_out + NC;                    // NC bf16 (second half)

    dim3 blk328(32, 8);
    dim3 offaw_grid(1, 256);
    int  lnf_half = (BN_TOT / 2) / 4;   // 4096 blocks, 4 rows each
    unsigned addb = (unsigned)(NC / 8 / 256);

    // voxelize
    mask_kernel<<<BN_TOT / 256, 256, 0, stream>>>(lidar, mask);
    order_kernel<<<BDIM, 256, 0, stream>>>(mask, order, nvalid);
    ref_kernel<<<BN_TOT / 256, 256, 0, stream>>>(order, nvalid, refb);
    pack_q_kernel<<<dim3(NDIM / 32, CDIM / 32, BDIM), blk328, 0, stream>>>(lidar, order, nvalid, q);
    bev_conv_kernel<<<dim3(NDIM / 32, CDIM / 32, BDIM), blk328, 0, stream>>>(bev, featT);

    // hoisted weight conversions (all layers at once)
    tconv_b_kernel<<<dim3(16, 16, 6), blk328, 0, stream>>>(Wv,   wtv);
    tconv_b_kernel<<<dim3(16, 16, 6), blk328, 0, stream>>>(Wout, wtout);
    tconv_b_kernel<<<dim3(16, 16, 6), blk328, 0, stream>>>(W1,   wt1);
    tconv_b_kernel<<<dim3(16, 16, 6), blk328, 0, stream>>>(W2,   wt2);
    tconv_b_kernel<<<dim3(16, 16, 1), blk328, 0, stream>>>(pe_W2, wtpe);
    tconv_offaw_b_kernel<<<dim3(16, 3, 6), blk328, 0, stream>>>(Woff, Waw, offawt);

    // positional embedding: qpos_bf = relu(BN(ref@peW1)) @ peW2
    pe_hidden_kernel<<<BN_TOT, 128, 0, stream>>>(refb, peW1, peg, peb, pem, pev, actA);
    gemm_bf16<<<256, 512, 0, stream>>>(actA, wtpe, nullptr, qpos_bf, 0);

    // x0 = q0 + qpos -> actB
    add_bf_kernel<<<addb, 256, 0, stream>>>(q, qpos_bf, actB);

    for (int i = 0; i < LNUM; ++i) {
        // off/aw = x @ [Woff|Waw] + bias   (x lives in actB)
        gemm_offaw<<<offaw_grid, 256, 0, stream>>>(actB, offawt + (size_t)i * 96 * 512,
                                                   boff + i * 64, baw + i * 32, offb, awb);
        // v = featT @ Wv + bv -> actA
        gemm_bf16<<<256, 512, 0, stream>>>(featT, wtv + (size_t)i * WSZ,
                                           bv + i * CDIM, actA, 0);
        // sampled -> actB (x dead after offaw)
        sample_kernel<<<BN_TOT / 4, 256, 0, stream>>>(refb, offb, awb, actA, actB);
        // Y1 = sampled @ Wout + bout + q  (fp32, 16K-row chunks via actA; v dead)
        // q = LN1(Y1)
        for (int c = 0; c < 2; ++c) {
            gemm_residf<<<512, 256, 0, stream>>>(
                actB + c * HALF, wtout + (size_t)i * WSZ, bout + i * CDIM,
                q + c * HALF, actAf);
            ln_f<<<lnf_half, 256, 0, stream>>>(
                actAf, ln1g + i * CDIM, ln1b + i * CDIM, q + c * HALF);
        }
        // h = relu(q @ W1) -> actA (Y1 dead)
        gemm_bf16<<<256, 512, 0, stream>>>(q, wt1 + (size_t)i * WSZ, nullptr, actA, 1);
        // Y2 = h @ W2 + q  (fp32 chunks via actB; sampled dead); q = LN2(Y2)
        for (int c = 0; c < 2; ++c) {
            gemm_residf<<<512, 256, 0, stream>>>(
                actA + c * HALF, wt2 + (size_t)i * WSZ, nullptr,
                q + c * HALF, actBf);
            ln_f<<<lnf_half, 256, 0, stream>>>(
                actBf, ln2g + i * CDIM, ln2b + i * CDIM, q + c * HALF);
        }
        // x_{i+1} = q + qpos -> actB (Y2 dead; skip on last layer)
        if (i < LNUM - 1)
            add_bf_kernel<<<addb, 256, 0, stream>>>(q, qpos_bf, actB);
    }

    // scatter back to dense (B, C, H, W) — overwrites all of d_out
    scatter_kernel<<<dim3(NDIM / 32, CDIM / 32, BDIM), blk328, 0, stream>>>(
        q, order, nvalid, (float*)d_out);
}

// Round 8
// 1698.482 us; speedup vs baseline: 1.1041x; 1.0613x over previous
//
#include <hip/hip_runtime.h>
#include <cstdint>
#include <cstddef>

// Problem constants
#define BDIM 2
#define CDIM 512
#define HDIM 128
#define WDIM 128
#define NDIM (HDIM * WDIM)        // 16384
#define LNUM 6
#define NHEADS 8
#define HEAD_DIM 64
#define NPTS 4
#define BN_TOT (BDIM * NDIM)      // 32768

typedef unsigned short u16;
typedef __attribute__((ext_vector_type(8))) short bf16x8;   // 8 bf16 = 4 VGPRs
typedef __attribute__((ext_vector_type(4))) float f32x4;    // MFMA accum

__device__ __forceinline__ u16 f2bf(float x) {              // RNE fp32->bf16
    unsigned u = __float_as_uint(x);
    u += 0x7fffu + ((u >> 16) & 1u);
    return (u16)(u >> 16);
}
__device__ __forceinline__ float bf2f(u16 h) {
    return __uint_as_float(((unsigned)h) << 16);
}

__device__ __forceinline__ void load_lds16(const void* g, void* l) {
    // async global->LDS, 16B/lane; LDS dest = wave-uniform base + lane*16
    __builtin_amdgcn_global_load_lds(
        (const __attribute__((address_space(1))) void*)g,
        (__attribute__((address_space(3))) void*)l, 16, 0, 0);
}

// counted vmem waits (literal-only in asm string)
__device__ __forceinline__ void wait_vm16() { asm volatile("s_waitcnt vmcnt(16)" ::: "memory"); }
__device__ __forceinline__ void wait_vm12() { asm volatile("s_waitcnt vmcnt(12)" ::: "memory"); }
__device__ __forceinline__ void wait_vm8()  { asm volatile("s_waitcnt vmcnt(8)" ::: "memory"); }
__device__ __forceinline__ void wait_vm4()  { asm volatile("s_waitcnt vmcnt(4)" ::: "memory"); }
__device__ __forceinline__ void wait_vm0()  { asm volatile("s_waitcnt vmcnt(0)" ::: "memory"); }
__device__ __forceinline__ void sbar()  { __builtin_amdgcn_s_barrier(); }
__device__ __forceinline__ void spin()  { __builtin_amdgcn_sched_barrier(0); }

// ---------------------------------------------------------------------------
// voxelization: mask / order / ref / pack_q(bf16)
// ---------------------------------------------------------------------------
__global__ void mask_kernel(const float* __restrict__ lidar, int* __restrict__ mask)
{
    int idx = blockIdx.x * blockDim.x + threadIdx.x;
    if (idx >= BN_TOT) return;
    int b = idx / NDIM;
    int n = idx - b * NDIM;
    const float* p = lidar + (size_t)b * CDIM * NDIM + n;
    int ok = 1;
#pragma unroll 8
    for (int c = 0; c < CDIM; ++c)
        ok &= (p[(size_t)c * NDIM] != 0.0f);
    mask[idx] = ok;
}

__global__ void order_kernel(const int* __restrict__ mask, int* __restrict__ order,
                             int* __restrict__ nvalid)
{
    int b = blockIdx.x;
    const int* m = mask + b * NDIM;
    int* ord = order + b * NDIM;
    __shared__ int part[256];
    __shared__ int totalValid;
    int t = threadIdx.x;
    const int CHUNK = NDIM / 256;
    int base = t * CHUNK;
    int cnt = 0;
    for (int i = 0; i < CHUNK; ++i) cnt += m[base + i];
    part[t] = cnt;
    __syncthreads();
    for (int s = 1; s < 256; s <<= 1) {
        int v = (t >= s) ? part[t - s] : 0;
        __syncthreads();
        part[t] += v;
        __syncthreads();
    }
    if (t == 255) { totalValid = part[255]; nvalid[b] = part[255]; }
    __syncthreads();
    int validBefore = (t == 0) ? 0 : part[t - 1];
    int nv = totalValid;
    for (int i = 0; i < CHUNK; ++i) {
        int n = base + i;
        if (m[n]) { ord[validBefore] = n; validBefore++; }
        else      { int invBefore = n - validBefore; ord[nv + invBefore] = n; }
    }
}

__global__ void ref_kernel(const int* __restrict__ order, const int* __restrict__ nvalid,
                           float* __restrict__ ref)
{
    int idx = blockIdx.x * blockDim.x + threadIdx.x;
    if (idx >= BN_TOT) return;
    int b = idx / NDIM;
    int j = idx - b * NDIM;
    int n = order[idx];
    float flag = (j < nvalid[b]) ? 1.0f : 0.0f;
    int hh = n / WDIM;
    int ww = n - hh * WDIM;
    ref[(size_t)idx * 2 + 0] = ((float)ww / (float)WDIM) * flag;
    ref[(size_t)idx * 2 + 1] = ((float)hh / (float)HDIM) * flag;
}

__global__ void pack_q_kernel(const float* __restrict__ lidar, const int* __restrict__ order,
                              const int* __restrict__ nvalid, u16* __restrict__ q)
{
    __shared__ float tile[32][33];
    __shared__ int ord_s[32];
    int b  = blockIdx.z;
    int j0 = blockIdx.x * 32;
    int c0 = blockIdx.y * 32;
    int tx = threadIdx.x, ty = threadIdx.y;
    if (ty == 0) ord_s[tx] = order[b * NDIM + j0 + tx];
    __syncthreads();
    const float* src = lidar + (size_t)b * CDIM * NDIM;
#pragma unroll
    for (int k = 0; k < 4; ++k) {
        int cl = ty * 4 + k;
        tile[cl][tx] = src[(size_t)(c0 + cl) * NDIM + ord_s[tx]];
    }
    __syncthreads();
    int nv = nvalid[b];
#pragma unroll
    for (int k = 0; k < 4; ++k) {
        int jl = ty * 4 + k;
        int j = j0 + jl;
        float f = (j < nv) ? 1.0f : 0.0f;
        q[((size_t)b * NDIM + j) * CDIM + c0 + tx] = f2bf(tile[tx][jl] * f);
    }
}

// final scatter: out[b,c,order[j]] = q(bf16)[b,j,c] * valid  (fp32 out)
__global__ void scatter_kernel(const u16* __restrict__ q, const int* __restrict__ order,
                               const int* __restrict__ nvalid, float* __restrict__ out)
{
    __shared__ float tile[32][33];
    __shared__ int ord_s[32];
    int b  = blockIdx.z;
    int j0 = blockIdx.x * 32;
    int c0 = blockIdx.y * 32;
    int tx = threadIdx.x, ty = threadIdx.y;
    if (ty == 0) ord_s[tx] = order[b * NDIM + j0 + tx];
    __syncthreads();
    int nv = nvalid[b];
#pragma unroll
    for (int k = 0; k < 4; ++k) {
        int jl = ty * 4 + k;
        int j = j0 + jl;
        float f = (j < nv) ? 1.0f : 0.0f;
        tile[jl][tx] = bf2f(q[((size_t)b * NDIM + j) * CDIM + c0 + tx]) * f;
    }
    __syncthreads();
    float* dst = out + (size_t)b * CDIM * NDIM;
#pragma unroll
    for (int k = 0; k < 4; ++k) {
        int cl = ty * 4 + k;
        dst[(size_t)(c0 + cl) * NDIM + ord_s[tx]] = tile[tx][cl];
    }
}

// ---------------------------------------------------------------------------
// batched weight transpose-convert: src fp32 [z][512][512] -> dst bf16 [z][N][K]
// ---------------------------------------------------------------------------
__global__ void tconv_b_kernel(const float* __restrict__ src0, u16* __restrict__ dst0)
{
    __shared__ float t[32][33];
    int z = blockIdx.z;
    const float* src = src0 + (size_t)z * 512 * 512;
    u16* dst = dst0 + (size_t)z * 512 * 512;
    int k0 = blockIdx.x * 32, n0 = blockIdx.y * 32;
    int tx = threadIdx.x, ty = threadIdx.y;
#pragma unroll
    for (int j = 0; j < 4; ++j) {
        int kl = ty * 4 + j;
        t[kl][tx] = src[(size_t)(k0 + kl) * 512 + n0 + tx];
    }
    __syncthreads();
#pragma unroll
    for (int j = 0; j < 4; ++j) {
        int nl = ty * 4 + j;
        dst[(size_t)(n0 + nl) * 512 + k0 + tx] = f2bf(t[tx][nl]);
    }
}

// batched: Woff [z][512][64] + Waw [z][512][32] -> dst bf16 [z][96][512]
__global__ void tconv_offaw_b_kernel(const float* __restrict__ woff0,
                                     const float* __restrict__ waw0,
                                     u16* __restrict__ dst0)
{
    __shared__ float t[32][33];
    int z = blockIdx.z;
    const float* woff = woff0 + (size_t)z * 512 * 64;
    const float* waw  = waw0 + (size_t)z * 512 * 32;
    u16* dst = dst0 + (size_t)z * 96 * 512;
    int k0 = blockIdx.x * 32, n0 = blockIdx.y * 32;
    int tx = threadIdx.x, ty = threadIdx.y;
#pragma unroll
    for (int j = 0; j < 4; ++j) {
        int kl = ty * 4 + j;
        int n = n0 + tx;
        float v = (n < 64) ? woff[(size_t)(k0 + kl) * 64 + n]
                           : waw[(size_t)(k0 + kl) * 32 + (n - 64)];
        t[kl][tx] = v;
    }
    __syncthreads();
#pragma unroll
    for (int j = 0; j < 4; ++j) {
        int nl = ty * 4 + j;
        dst[(size_t)(n0 + nl) * 512 + k0 + tx] = f2bf(t[tx][nl]);
    }
}

// bev (B,C,N) fp32 -> featT (B,N,C) bf16
__global__ void bev_conv_kernel(const float* __restrict__ bev, u16* __restrict__ dst)
{
    __shared__ float t[32][33];
    int b  = blockIdx.z;
    int n0 = blockIdx.x * 32;
    int c0 = blockIdx.y * 32;
    int tx = threadIdx.x, ty = threadIdx.y;
    const float* src = bev + (size_t)b * CDIM * NDIM;
#pragma unroll
    for (int j = 0; j < 4; ++j) {
        int cl = ty * 4 + j;
        t[cl][tx] = src[(size_t)(c0 + cl) * NDIM + n0 + tx];
    }
    __syncthreads();
#pragma unroll
    for (int j = 0; j < 4; ++j) {
        int nl = ty * 4 + j;
        dst[((size_t)b * NDIM + n0 + nl) * CDIM + c0 + tx] = f2bf(t[tx][nl]);
    }
}

// ---------------------------------------------------------------------------
// PE hidden: h = relu(BN(ref @ pe_W1))  -> bf16
// ---------------------------------------------------------------------------
__global__ void pe_hidden_kernel(const float* __restrict__ ref, const float* __restrict__ W1,
                                 const float* __restrict__ g, const float* __restrict__ bb,
                                 const float* __restrict__ m, const float* __restrict__ v,
                                 u16* __restrict__ out)
{
    int row = blockIdx.x;
    float r0 = ref[(size_t)row * 2 + 0];
    float r1 = ref[(size_t)row * 2 + 1];
    for (int c = threadIdx.x; c < CDIM; c += blockDim.x) {
        float pe = r0 * W1[c] + r1 * W1[CDIM + c];
        pe = (pe - m[c]) * rsqrtf(v[c] + 1e-5f) * g[c] + bb[c];
        out[(size_t)row * CDIM + c] = f2bf(fmaxf(pe, 0.0f));
    }
}

// ---------------------------------------------------------------------------
// x = q(bf16) + qpos(bf16) -> bf16 ; 8 elements/thread
// ---------------------------------------------------------------------------
__global__ void add_bf_kernel(const u16* __restrict__ q, const u16* __restrict__ qpos,
                              u16* __restrict__ x)
{
    size_t i = (size_t)blockIdx.x * blockDim.x + threadIdx.x;  // 8-el group
    uint4 qa = ((const uint4*)q)[i];
    uint4 pv = ((const uint4*)qpos)[i];
    unsigned qw[4] = {qa.x, qa.y, qa.z, qa.w};
    unsigned pw[4] = {pv.x, pv.y, pv.z, pv.w};
    unsigned rw[4];
#pragma unroll
    for (int k = 0; k < 4; ++k) {
        float a0 = bf2f((u16)(qw[k] & 0xffff)), a1 = bf2f((u16)(qw[k] >> 16));
        float p0 = bf2f((u16)(pw[k] & 0xffff)), p1 = bf2f((u16)(pw[k] >> 16));
        rw[k] = (unsigned)f2bf(a0 + p0) | ((unsigned)f2bf(a1 + p1) << 16);
    }
    uint4 r; r.x = rw[0]; r.y = rw[1]; r.z = rw[2]; r.w = rw[3];
    ((uint4*)x)[i] = r;
}

// ---------------------------------------------------------------------------
// MFMA bf16 GEMM — v6: 256x256 tile, BK=32, 8 waves (512 thr).
// 4-buffer LDS prefetch depth-3 + two raw barriers + counted vmcnt; XCD-aware
// swizzle (grid-size-parametric: works for any nwg % 8 == 0).
// ---------------------------------------------------------------------------
__global__ __launch_bounds__(512) void gemm_bf16(
    const u16* __restrict__ A, const u16* __restrict__ Bt,
    const float* __restrict__ bias, u16* __restrict__ outB, int relu)
{
    __shared__ u16 As[4][256 * 32];   // 64 KB
    __shared__ u16 Bs[4][256 * 32];   // 64 KB
    int tid = threadIdx.x;
    int wave = tid >> 6, lane = tid & 63;
    int wr = wave >> 2, wc = wave & 3;           // wave grid 2 (M) x 4 (N)
    int quad = lane >> 4, l15 = lane & 15;
    int lid = blockIdx.x;
    int cpx = gridDim.x >> 3;
    int tsw = (lid & 7) * cpx + (lid >> 3);      // XCD-contiguous tile id
    int bm = (tsw >> 1) * 256, bn = (tsw & 1) * 256;

    f32x4 acc[8][4];
#pragma unroll
    for (int i = 0; i < 8; ++i)
#pragma unroll
        for (int j = 0; j < 4; ++j) { f32x4 z = {0.f, 0.f, 0.f, 0.f}; acc[i][j] = z; }

    int c0 = wave * 2, c1 = wave * 2 + 1;
    const u16* Ag0 = A  + (size_t)(bm + c0 * 16 + (lane >> 2)) * 512 + (lane & 3) * 8;
    const u16* Ag1 = A  + (size_t)(bm + c1 * 16 + (lane >> 2)) * 512 + (lane & 3) * 8;
    const u16* Bg0 = Bt + (size_t)(bn + c0 * 16 + (lane >> 2)) * 512 + (lane & 3) * 8;
    const u16* Bg1 = Bt + (size_t)(bn + c1 * 16 + (lane >> 2)) * 512 + (lane & 3) * 8;

#pragma unroll
    for (int k = 0; k < 3; ++k) {
        load_lds16(Ag0 + k * 32, &As[k][c0 * 512]);
        load_lds16(Ag1 + k * 32, &As[k][c1 * 512]);
        load_lds16(Bg0 + k * 32, &Bs[k][c0 * 512]);
        load_lds16(Bg1 + k * 32, &Bs[k][c1 * 512]);
    }

    for (int it = 0; it < 16; ++it) {
        sbar();  spin();                    // prev readers of target buffer done
        int cur = it & 3;
        if (it < 13) {
            int nb = (it + 3) & 3;
            int kn = (it + 3) * 32;
            load_lds16(Ag0 + kn, &As[nb][c0 * 512]);
            load_lds16(Ag1 + kn, &As[nb][c1 * 512]);
            load_lds16(Bg0 + kn, &Bs[nb][c0 * 512]);
            load_lds16(Bg1 + kn, &Bs[nb][c1 * 512]);
            wait_vm12();                    // own tile-it loads landed; 3 in flight
        } else if (it == 13) {
            wait_vm8();
        } else if (it == 14) {
            wait_vm4();
        } else {
            wait_vm0();
        }
        sbar();  spin();                    // everyone's tile-it loads landed
        bf16x8 av[8], bv[4];
#pragma unroll
        for (int mi = 0; mi < 8; ++mi)
            av[mi] = *(const bf16x8*)&As[cur][(wr * 128 + mi * 16 + l15) * 32 + quad * 8];
#pragma unroll
        for (int ni = 0; ni < 4; ++ni)
            bv[ni] = *(const bf16x8*)&Bs[cur][(wc * 64 + ni * 16 + l15) * 32 + quad * 8];
#pragma unroll
        for (int mi = 0; mi < 8; ++mi)
#pragma unroll
            for (int ni = 0; ni < 4; ++ni)
                acc[mi][ni] = __builtin_amdgcn_mfma_f32_16x16x32_bf16(
                    av[mi], bv[ni], acc[mi][ni], 0, 0, 0);
    }

    int rowb = bm + wr * 128;
    int colb = bn + wc * 64;
#pragma unroll
    for (int mi = 0; mi < 8; ++mi) {
#pragma unroll
        for (int ni = 0; ni < 4; ++ni) {
            int col = colb + ni * 16 + l15;
            float bi = bias ? bias[col] : 0.0f;
#pragma unroll
            for (int r = 0; r < 4; ++r) {
                int row = rowb + mi * 16 + quad * 4 + r;
                float val = acc[mi][ni][r] + bi;
                if (relu) val = fmaxf(val, 0.0f);
                outB[(size_t)row * 512 + col] = f2bf(val);
            }
        }
    }
}

// ---------------------------------------------------------------------------
// gemm_residf — v7: 256x256 depth-3 structure (same as gemm_bf16 v6); epilogue
// writes Y = acc + bias + resid in **fp32** (no rounding before LN).
// Works full-M (grid 256) or chunked fallback (grid 128); swizzle is
// grid-size-parametric.
// ---------------------------------------------------------------------------
__global__ __launch_bounds__(512) void gemm_residf(
    const u16* __restrict__ A, const u16* __restrict__ Bt,
    const float* __restrict__ bias, const u16* __restrict__ resid,
    float* __restrict__ outY)
{
    __shared__ u16 As[4][256 * 32];
    __shared__ u16 Bs[4][256 * 32];
    int tid = threadIdx.x;
    int wave = tid >> 6, lane = tid & 63;
    int wr = wave >> 2, wc = wave & 3;
    int quad = lane >> 4, l15 = lane & 15;
    int lid = blockIdx.x;
    int cpx = gridDim.x >> 3;
    int tsw = (lid & 7) * cpx + (lid >> 3);
    int bm = (tsw >> 1) * 256, bn = (tsw & 1) * 256;

    f32x4 acc[8][4];
#pragma unroll
    for (int i = 0; i < 8; ++i)
#pragma unroll
        for (int j = 0; j < 4; ++j) { f32x4 z = {0.f, 0.f, 0.f, 0.f}; acc[i][j] = z; }

    int c0 = wave * 2, c1 = wave * 2 + 1;
    const u16* Ag0 = A  + (size_t)(bm + c0 * 16 + (lane >> 2)) * 512 + (lane & 3) * 8;
    const u16* Ag1 = A  + (size_t)(bm + c1 * 16 + (lane >> 2)) * 512 + (lane & 3) * 8;
    const u16* Bg0 = Bt + (size_t)(bn + c0 * 16 + (lane >> 2)) * 512 + (lane & 3) * 8;
    const u16* Bg1 = Bt + (size_t)(bn + c1 * 16 + (lane >> 2)) * 512 + (lane & 3) * 8;

#pragma unroll
    for (int k = 0; k < 3; ++k) {
        load_lds16(Ag0 + k * 32, &As[k][c0 * 512]);
        load_lds16(Ag1 + k * 32, &As[k][c1 * 512]);
        load_lds16(Bg0 + k * 32, &Bs[k][c0 * 512]);
        load_lds16(Bg1 + k * 32, &Bs[k][c1 * 512]);
    }

    for (int it = 0; it < 16; ++it) {
        sbar();  spin();
        int cur = it & 3;
        if (it < 13) {
            int nb = (it + 3) & 3;
            int kn = (it + 3) * 32;
            load_lds16(Ag0 + kn, &As[nb][c0 * 512]);
            load_lds16(Ag1 + kn, &As[nb][c1 * 512]);
            load_lds16(Bg0 + kn, &Bs[nb][c0 * 512]);
            load_lds16(Bg1 + kn, &Bs[nb][c1 * 512]);
            wait_vm12();
        } else if (it == 13) {
            wait_vm8();
        } else if (it == 14) {
            wait_vm4();
        } else {
            wait_vm0();
        }
        sbar();  spin();
        bf16x8 av[8], bv[4];
#pragma unroll
        for (int mi = 0; mi < 8; ++mi)
            av[mi] = *(const bf16x8*)&As[cur][(wr * 128 + mi * 16 + l15) * 32 + quad * 8];
#pragma unroll
        for (int ni = 0; ni < 4; ++ni)
            bv[ni] = *(const bf16x8*)&Bs[cur][(wc * 64 + ni * 16 + l15) * 32 + quad * 8];
#pragma unroll
        for (int mi = 0; mi < 8; ++mi)
#pragma unroll
            for (int ni = 0; ni < 4; ++ni)
                acc[mi][ni] = __builtin_amdgcn_mfma_f32_16x16x32_bf16(
                    av[mi], bv[ni], acc[mi][ni], 0, 0, 0);
    }

    int rowb = bm + wr * 128;
    int colb = bn + wc * 64;
#pragma unroll
    for (int mi = 0; mi < 8; ++mi) {
#pragma unroll
        for (int ni = 0; ni < 4; ++ni) {
            int col = colb + ni * 16 + l15;
            float bi = bias ? bias[col] : 0.0f;
#pragma unroll
            for (int r = 0; r < 4; ++r) {
                int row = rowb + mi * 16 + quad * 4 + r;
                size_t off = (size_t)row * 512 + col;
                outY[off] = acc[mi][ni][r] + bi + bf2f(resid[off]);
            }
        }
    }
}

// ---------------------------------------------------------------------------
// ln_f: per-row LayerNorm over 512 cols of fp32 Y. One wave per row.
// fp32 stats + fp32 normalize, single bf16 rounding at the output.
// Optional fused x = (y_fp32 + qpos) -> outX (same math as the r0-r3 verified
// fused kernel: qpos added to UNROUNDED y, single rounding).
// ---------------------------------------------------------------------------
__global__ __launch_bounds__(256) void ln_f(
    const float* __restrict__ Y, const float* __restrict__ g,
    const float* __restrict__ bta, u16* __restrict__ outQ,
    const u16* __restrict__ qpos, u16* __restrict__ outX)
{
    int row  = blockIdx.x * 4 + (threadIdx.x >> 6);
    int lane = threadIdx.x & 63;
    size_t base = (size_t)row * CDIM + lane * 8;

    float4 y0 = *(const float4*)(Y + base);
    float4 y1 = *(const float4*)(Y + base + 4);
    float v[8] = {y0.x, y0.y, y0.z, y0.w, y1.x, y1.y, y1.z, y1.w};

    float s = 0.f, s2 = 0.f;
#pragma unroll
    for (int j = 0; j < 8; ++j) { s += v[j]; s2 += v[j] * v[j]; }
#pragma unroll
    for (int m = 1; m < 64; m <<= 1) {
        s  += __shfl_xor(s, m, 64);
        s2 += __shfl_xor(s2, m, 64);
    }
    float mu = s * (1.0f / 512.0f);
    float var = s2 * (1.0f / 512.0f) - mu * mu;
    float iv = rsqrtf(var + 1e-5f);

    int c0 = lane * 8;
    float4 g0 = *(const float4*)(g + c0);
    float4 g1 = *(const float4*)(g + c0 + 4);
    float4 b0 = *(const float4*)(bta + c0);
    float4 b1 = *(const float4*)(bta + c0 + 4);
    float gl[8] = {g0.x, g0.y, g0.z, g0.w, g1.x, g1.y, g1.z, g1.w};
    float bl[8] = {b0.x, b0.y, b0.z, b0.w, b1.x, b1.y, b1.z, b1.w};

    float y[8];
#pragma unroll
    for (int j = 0; j < 8; ++j)
        y[j] = (v[j] - mu) * iv * gl[j] + bl[j];

    unsigned qw[4];
#pragma unroll
    for (int k = 0; k < 4; ++k)
        qw[k] = (unsigned)f2bf(y[2 * k]) | ((unsigned)f2bf(y[2 * k + 1]) << 16);
    uint4 qo; qo.x = qw[0]; qo.y = qw[1]; qo.z = qw[2]; qo.w = qw[3];
    *(uint4*)(outQ + base) = qo;

    if (outX) {
        uint4 pv = *(const uint4*)(qpos + base);
        unsigned pw[4] = {pv.x, pv.y, pv.z, pv.w};
        unsigned xw[4];
#pragma unroll
        for (int k = 0; k < 4; ++k) {
            float p0 = bf2f((u16)(pw[k] & 0xffff));
            float p1 = bf2f((u16)(pw[k] >> 16));
            xw[k] = (unsigned)f2bf(y[2 * k] + p0)
                  | ((unsigned)f2bf(y[2 * k + 1] + p1) << 16);
        }
        uint4 xo; xo.x = xw[0]; xo.y = xw[1]; xo.z = xw[2]; xo.w = xw[3];
        *(uint4*)(outX + base) = xo;
    }
}

// ---------------------------------------------------------------------------
// fused off+aw GEMM: A @ OffAwT[96][512] -> offb/awb. 3-buffer depth-2
// (wave-local staging, single barrier per step; vmcnt(16) steady).
// ---------------------------------------------------------------------------
__global__ __launch_bounds__(256) void gemm_offaw(
    const u16* __restrict__ A, const u16* __restrict__ Bt,
    const float* __restrict__ boff, const float* __restrict__ baw,
    u16* __restrict__ offb, u16* __restrict__ awb)
{
    __shared__ u16 As[3][128 * 32];
    __shared__ u16 Bs[3][128 * 32];
    int tid = threadIdx.x;
    int wave = tid >> 6, lane = tid & 63;
    int wr = wave >> 1, wc = wave & 1;
    int quad = lane >> 4, l15 = lane & 15;
    int bm = blockIdx.y * 128;

    f32x4 acc[4][4];
#pragma unroll
    for (int i = 0; i < 4; ++i)
#pragma unroll
        for (int j = 0; j < 4; ++j) { f32x4 z = {0.f, 0.f, 0.f, 0.f}; acc[i][j] = z; }

    // wave-local staging; B rows clamped at 95 (cols >=96 are discarded)
    const u16* Ag[4];
    const u16* Bg[4];
#pragma unroll
    for (int s = 0; s < 4; ++s) {
        Ag[s] = A + (size_t)(bm + wr * 64 + s * 16 + (lane >> 2)) * 512 + (lane & 3) * 8;
        int br = wc * 64 + s * 16 + (lane >> 2);
        if (br > 95) br = 95;
        Bg[s] = Bt + (size_t)br * 512 + (lane & 3) * 8;
    }

    // prologue: tiles 0,1 into buffers 0,1
#pragma unroll
    for (int k = 0; k < 2; ++k)
#pragma unroll
        for (int s = 0; s < 4; ++s) {
            load_lds16(Ag[s] + k * 32, &As[k][(wr * 4 + s) * 512]);
            load_lds16(Bg[s] + k * 32, &Bs[k][(wc * 4 + s) * 512]);
        }

    for (int it = 0; it < 16; ++it) {
        sbar();
        int cur = it % 3;
        if (it < 14) {
            int nb = (it + 2) % 3;
            int kn = (it + 2) * 32;
#pragma unroll
            for (int s = 0; s < 4; ++s) {
                load_lds16(Ag[s] + kn, &As[nb][(wr * 4 + s) * 512]);
                load_lds16(Bg[s] + kn, &Bs[nb][(wc * 4 + s) * 512]);
            }
            wait_vm16();
        } else if (it == 14) {
            wait_vm8();
        } else {
            wait_vm0();
        }
        bf16x8 av[4], bv[4];
#pragma unroll
        for (int mi = 0; mi < 4; ++mi)
            av[mi] = *(const bf16x8*)&As[cur][(wr * 64 + mi * 16 + l15) * 32 + quad * 8];
#pragma unroll
        for (int ni = 0; ni < 4; ++ni)
            bv[ni] = *(const bf16x8*)&Bs[cur][(wc * 64 + ni * 16 + l15) * 32 + quad * 8];
#pragma unroll
        for (int mi = 0; mi < 4; ++mi)
#pragma unroll
            for (int ni = 0; ni < 4; ++ni)
                acc[mi][ni] = __builtin_amdgcn_mfma_f32_16x16x32_bf16(
                    av[mi], bv[ni], acc[mi][ni], 0, 0, 0);
    }

    int rowb = bm + wr * 64;
#pragma unroll
    for (int mi = 0; mi < 4; ++mi) {
#pragma unroll
        for (int ni = 0; ni < 4; ++ni) {
            int col = wc * 64 + ni * 16 + l15;
            if (col < 96) {
                float bi = (col < 64) ? boff[col] : baw[col - 64];
#pragma unroll
                for (int r = 0; r < 4; ++r) {
                    int row = rowb + mi * 16 + quad * 4 + r;
                    float val = acc[mi][ni][r] + bi;
                    if (col < 64) offb[(size_t)row * 64 + col] = f2bf(val);
                    else          awb[(size_t)row * 32 + (col - 64)] = f2bf(val);
                }
            }
        }
    }
}

// ---------------------------------------------------------------------------
// deformable sampling: one wave per (b,j); lane = (head, 8 channels)
// ---------------------------------------------------------------------------
__global__ __launch_bounds__(256) void sample_kernel(
    const float* __restrict__ ref, const u16* __restrict__ off,
    const u16* __restrict__ aw, const u16* __restrict__ v,
    u16* __restrict__ out)
{
    int bj = blockIdx.x * 4 + (threadIdx.x >> 6);   // b*N + j
    int lane = threadIdx.x & 63;
    int h  = lane >> 3;
    int d8 = (lane & 7) * 8;
    int b  = bj >> 14;

    float rx = ref[(size_t)bj * 2 + 0];
    float ry = ref[(size_t)bj * 2 + 1];
    uint4 offv = *(const uint4*)(off + (size_t)bj * 64 + h * 8);
    uint2 awv  = *(const uint2*)(aw + (size_t)bj * 32 + h * 4);

    float l0 = bf2f((u16)(awv.x & 0xffff)), l1 = bf2f((u16)(awv.x >> 16));
    float l2 = bf2f((u16)(awv.y & 0xffff)), l3 = bf2f((u16)(awv.y >> 16));
    float mx = fmaxf(fmaxf(l0, l1), fmaxf(l2, l3));
    float e[4];
    e[0] = expf(l0 - mx); e[1] = expf(l1 - mx);
    e[2] = expf(l2 - mx); e[3] = expf(l3 - mx);
    float inv_es = 1.0f / (e[0] + e[1] + e[2] + e[3]);

    const u16* vb = v + (size_t)b * NDIM * CDIM + h * HEAD_DIM + d8;
    float acc[8] = {0.f, 0.f, 0.f, 0.f, 0.f, 0.f, 0.f, 0.f};
    unsigned ow[4] = {offv.x, offv.y, offv.z, offv.w};

#pragma unroll
    for (int p = 0; p < NPTS; ++p) {
        float ox = bf2f((u16)(ow[p] & 0xffff));
        float oy = bf2f((u16)(ow[p] >> 16));
        float X = rx * (float)WDIM + ox - 0.5f;
        float Y = ry * (float)HDIM + oy - 0.5f;
        float x0f = floorf(X), y0f = floorf(Y);
        float wx = X - x0f, wy = Y - y0f;
        int x0 = (int)x0f, y0 = (int)y0f;
        float ep = e[p];
#pragma unroll
        for (int cy = 0; cy < 2; ++cy) {
            int yy = y0 + cy;
            float wyc = cy ? wy : (1.0f - wy);
            int yin = (yy >= 0) & (yy < HDIM);
            int yc = min(max(yy, 0), HDIM - 1);
#pragma unroll
            for (int cx = 0; cx < 2; ++cx) {
                int xx = x0 + cx;
                float wxc = cx ? wx : (1.0f - wx);
                int xin = (xx >= 0) & (xx < WDIM);
                int xc = min(max(xx, 0), WDIM - 1);
                float wgt = ep * wyc * wxc * (float)(yin & xin);
                uint4 vv = *(const uint4*)(vb + (size_t)(yc * WDIM + xc) * CDIM);
                acc[0] += wgt * bf2f((u16)(vv.x & 0xffff));
                acc[1] += wgt * bf2f((u16)(vv.x >> 16));
                acc[2] += wgt * bf2f((u16)(vv.y & 0xffff));
                acc[3] += wgt * bf2f((u16)(vv.y >> 16));
                acc[4] += wgt * bf2f((u16)(vv.z & 0xffff));
                acc[5] += wgt * bf2f((u16)(vv.z >> 16));
                acc[6] += wgt * bf2f((u16)(vv.w & 0xffff));
                acc[7] += wgt * bf2f((u16)(vv.w >> 16));
            }
        }
    }
    uint4 r;
    r.x = (unsigned)f2bf(acc[0] * inv_es) | ((unsigned)f2bf(acc[1] * inv_es) << 16);
    r.y = (unsigned)f2bf(acc[2] * inv_es) | ((unsigned)f2bf(acc[3] * inv_es) << 16);
    r.z = (unsigned)f2bf(acc[4] * inv_es) | ((unsigned)f2bf(acc[5] * inv_es) << 16);
    r.w = (unsigned)f2bf(acc[6] * inv_es) | ((unsigned)f2bf(acc[7] * inv_es) << 16);
    *(uint4*)(out + (size_t)bj * CDIM + h * HEAD_DIM + d8) = r;
}

// ---------------------------------------------------------------------------
// launcher
// ---------------------------------------------------------------------------
extern "C" void kernel_launch(void* const* d_in, const int* in_sizes, int n_in,
                              void* d_out, int out_size, void* d_ws, size_t ws_size,
                              hipStream_t stream)
{
    const float* bev   = (const float*)d_in[0];
    const float* lidar = (const float*)d_in[1];
    const float* Wv    = (const float*)d_in[2];
    const float* bv    = (const float*)d_in[3];
    const float* Woff  = (const float*)d_in[4];
    const float* boff  = (const float*)d_in[5];
    const float* Waw   = (const float*)d_in[6];
    const float* baw   = (const float*)d_in[7];
    const float* Wout  = (const float*)d_in[8];
    const float* bout  = (const float*)d_in[9];
    const float* ln1g  = (const float*)d_in[10];
    const float* ln1b  = (const float*)d_in[11];
    const float* W1    = (const float*)d_in[12];
    const float* W2    = (const float*)d_in[13];
    const float* ln2g  = (const float*)d_in[14];
    const float* ln2b  = (const float*)d_in[15];
    const float* peW1  = (const float*)d_in[16];
    const float* peg   = (const float*)d_in[17];
    const float* peb   = (const float*)d_in[18];
    const float* pem   = (const float*)d_in[19];
    const float* pev   = (const float*)d_in[20];
    const float* pe_W2 = (const float*)d_in[21];

    const size_t NC   = (size_t)BN_TOT * CDIM;   // 16,777,216 elements
    const size_t HALF = NC / 2;                  // 16K rows worth
    const size_t WSZ  = 512 * 512;               // one square weight

    char* base = (char*)d_ws;
    u16* q      = (u16*)base;                           // NC bf16 (residual stream)
    u16* actA   = (u16*)(base + NC * 2);                // NC bf16 (v / h)
    u16* actB   = (u16*)(base + NC * 4);                // NC bf16 (x / sampled)
    float* actAf = (float*)actA;                        // fallback fp32 chunk view
    float* actBf = (float*)actB;                        // fallback fp32 chunk view
    u16* wt     = (u16*)(base + NC * 6);                // 25 x 512x512 bf16
    u16* wtv    = wt;                                   // [6]
    u16* wtout  = wt + 6 * WSZ;                         // [6]
    u16* wt1    = wt + 12 * WSZ;                        // [6]
    u16* wt2    = wt + 18 * WSZ;                        // [6]
    u16* wtpe   = wt + 24 * WSZ;                        // [1]
    u16* offawt = wt + 25 * WSZ;                        // 6 x 96x512 bf16
    u16* offb   = offawt + 6 * 96 * 512;                // BN x 64 bf16
    u16* awb    = offb + (size_t)BN_TOT * 64;           // BN x 32 bf16
    float* refb = (float*)(awb + (size_t)BN_TOT * 32);  // BN x 2 fp32
    int* mask   = (int*)(refb + (size_t)BN_TOT * 2);
    int* order  = mask + BN_TOT;
    int* nvalid = order + BN_TOT;
    // full-size fp32 Y buffer (64 MB) at base+128MiB; used only if ws allows.
    // (end of the allocations above is ~121 MB, so 128 MiB is clear of them.)
    const size_t YF_OFF  = (size_t)128 * 1024 * 1024;
    const size_t YF_NEED = YF_OFF + NC * sizeof(float);   // 192 MiB total
    float* yf = (ws_size >= YF_NEED) ? (float*)(base + YF_OFF) : nullptr;

    // d_out doubles as scratch until final scatter:
    u16* qpos_bf = (u16*)d_out;                         // NC bf16 (first half)
    u16* featT   = (u16*)d_out + NC;                    // NC bf16 (second half)

    dim3 blk328(32, 8);
    dim3 offaw_grid(1, 256);
    int  lnf_full = BN_TOT / 4;         // 8192 blocks, 4 rows each
    int  lnf_half = (BN_TOT / 2) / 4;   // 4096 blocks (fallback)
    unsigned addb = (unsigned)(NC / 8 / 256);

    // voxelize
    mask_kernel<<<BN_TOT / 256, 256, 0, stream>>>(lidar, mask);
    order_kernel<<<BDIM, 256, 0, stream>>>(mask, order, nvalid);
    ref_kernel<<<BN_TOT / 256, 256, 0, stream>>>(order, nvalid, refb);
    pack_q_kernel<<<dim3(NDIM / 32, CDIM / 32, BDIM), blk328, 0, stream>>>(lidar, order, nvalid, q);
    bev_conv_kernel<<<dim3(NDIM / 32, CDIM / 32, BDIM), blk328, 0, stream>>>(bev, featT);

    // hoisted weight conversions (all layers at once)
    tconv_b_kernel<<<dim3(16, 16, 6), blk328, 0, stream>>>(Wv,   wtv);
    tconv_b_kernel<<<dim3(16, 16, 6), blk328, 0, stream>>>(Wout, wtout);
    tconv_b_kernel<<<dim3(16, 16, 6), blk328, 0, stream>>>(W1,   wt1);
    tconv_b_kernel<<<dim3(16, 16, 6), blk328, 0, stream>>>(W2,   wt2);
    tconv_b_kernel<<<dim3(16, 16, 1), blk328, 0, stream>>>(pe_W2, wtpe);
    tconv_offaw_b_kernel<<<dim3(16, 3, 6), blk328, 0, stream>>>(Woff, Waw, offawt);

    // positional embedding: qpos_bf = relu(BN(ref@peW1)) @ peW2
    pe_hidden_kernel<<<BN_TOT, 128, 0, stream>>>(refb, peW1, peg, peb, pem, pev, actA);
    gemm_bf16<<<256, 512, 0, stream>>>(actA, wtpe, nullptr, qpos_bf, 0);

    // x0 = q0 + qpos -> actB
    add_bf_kernel<<<addb, 256, 0, stream>>>(q, qpos_bf, actB);

    for (int i = 0; i < LNUM; ++i) {
        // off/aw = x @ [Woff|Waw] + bias   (x lives in actB)
        gemm_offaw<<<offaw_grid, 256, 0, stream>>>(actB, offawt + (size_t)i * 96 * 512,
                                                   boff + i * 64, baw + i * 32, offb, awb);
        // v = featT @ Wv + bv -> actA
        gemm_bf16<<<256, 512, 0, stream>>>(featT, wtv + (size_t)i * WSZ,
                                           bv + i * CDIM, actA, 0);
        // sampled -> actB (x dead after offaw)
        sample_kernel<<<BN_TOT / 4, 256, 0, stream>>>(refb, offb, awb, actA, actB);

        if (yf) {
            // full-M path: Y fp32 in dedicated buffer, LN fused with qpos-add
            // Y1 = sampled @ Wout + bout + q ; q = LN1(Y1)
            gemm_residf<<<256, 512, 0, stream>>>(actB, wtout + (size_t)i * WSZ,
                                                 bout + i * CDIM, q, yf);
            ln_f<<<lnf_full, 256, 0, stream>>>(yf, ln1g + i * CDIM, ln1b + i * CDIM,
                                               q, nullptr, nullptr);
            // h = relu(q @ W1) -> actA (v dead)
            gemm_bf16<<<256, 512, 0, stream>>>(q, wt1 + (size_t)i * WSZ, nullptr, actA, 1);
            // Y2 = h @ W2 + q ; q = LN2(Y2); x_{i+1} = (y + qpos) -> actB
            gemm_residf<<<256, 512, 0, stream>>>(actA, wt2 + (size_t)i * WSZ,
                                                 nullptr, q, yf);
            ln_f<<<lnf_full, 256, 0, stream>>>(yf, ln2g + i * CDIM, ln2b + i * CDIM,
                                               q, qpos_bf,
                                               (i < LNUM - 1) ? actB : nullptr);
        } else {
            // fallback: 16K-row chunks through actA/actB fp32 views (r7 scheme)
            for (int c = 0; c < 2; ++c) {
                gemm_residf<<<128, 512, 0, stream>>>(
                    actB + c * HALF, wtout + (size_t)i * WSZ, bout + i * CDIM,
                    q + c * HALF, actAf);
                ln_f<<<lnf_half, 256, 0, stream>>>(
                    actAf, ln1g + i * CDIM, ln1b + i * CDIM, q + c * HALF,
                    nullptr, nullptr);
            }
            gemm_bf16<<<256, 512, 0, stream>>>(q, wt1 + (size_t)i * WSZ, nullptr, actA, 1);
            for (int c = 0; c < 2; ++c) {
                gemm_residf<<<128, 512, 0, stream>>>(
                    actA + c * HALF, wt2 + (size_t)i * WSZ, nullptr,
                    q + c * HALF, actBf);
                ln_f<<<lnf_half, 256, 0, stream>>>(
                    actBf, ln2g + i * CDIM, ln2b + i * CDIM, q + c * HALF,
                    nullptr, nullptr);
            }
            if (i < LNUM - 1)
                add_bf_kernel<<<addb, 256, 0, stream>>>(q, qpos_bf, actB);
        }
    }

    // scatter back to dense (B, C, H, W) — overwrites all of d_out
    scatter_kernel<<<dim3(NDIM / 32, CDIM / 32, BDIM), blk328, 0, stream>>>(
        q, order, nvalid, (float*)d_out);
}